// Round 2
// baseline (246.034 us; speedup 1.0000x reference)
//
#include <hip/hip_runtime.h>
#include <hip/hip_bf16.h>
#include <type_traits>
#include <cstdint>

typedef float  f32x4  __attribute__((ext_vector_type(4)));
typedef short  s16x8  __attribute__((ext_vector_type(8)));
typedef __bf16 bf16x8 __attribute__((ext_vector_type(8)));

// ---- MFMA wrapper: tolerant to builtin taking v8i16 or v8bf16 ----
template <typename V>
__device__ static inline auto mfma_try(V a, V b, f32x4 c, int)
    -> decltype(__builtin_amdgcn_mfma_f32_16x16x32_bf16(a, b, c, 0, 0, 0)) {
  return __builtin_amdgcn_mfma_f32_16x16x32_bf16(a, b, c, 0, 0, 0);
}
template <typename V>
__device__ static inline f32x4 mfma_try(V a, V b, f32x4 c, long) {
  return __builtin_amdgcn_mfma_f32_16x16x32_bf16(
      __builtin_bit_cast(bf16x8, a), __builtin_bit_cast(bf16x8, b), c, 0, 0, 0);
}
__device__ static inline f32x4 MFMA_BF16(s16x8 a, s16x8 b, f32x4 c) {
  return mfma_try(a, b, c, 0);
}

// ---- workspace layout (bf16 element offsets) ----
static constexpr size_t OFF_XTQ  = 0;         // [2][4096][256]
static constexpr size_t OFF_XTKV = 2097152;   // [2][4096][256]
static constexpr size_t OFF_WQ   = 4194304;   // [256][256]
static constexpr size_t OFF_WK   = 4259840;
static constexpr size_t OFF_WV   = 4325376;
static constexpr size_t OFF_WO   = 4390912;
static constexpr size_t OFF_Q    = 4456448;   // [2][4][4096][64]  (pre-scaled by 1/8)
static constexpr size_t OFF_K    = 6553600;   // [2][4][4096][64]
static constexpr size_t OFF_V    = 8650752;   // [2][4][64][4096]
static constexpr size_t OFF_AO   = 10747904;  // [2][4096][256]

// =====================================================================
// prep: transpose+cvt x_q/x_kv [C][S]f32 -> [S][C]bf16 ; cvt weights
// grid (512,1,3) block 256
// =====================================================================
__global__ __launch_bounds__(256) void prep_kernel(
    const float* __restrict__ xq, const float* __restrict__ xkv,
    const float* __restrict__ wq, const float* __restrict__ wk,
    const float* __restrict__ wv, const float* __restrict__ wo,
    __bf16* __restrict__ ws) {
  __shared__ __bf16 lds[64 * 66];
  const int t = threadIdx.x;
  const int z = blockIdx.z;
  if (z < 2) {
    const float* src = (z == 0) ? xq : xkv;
    __bf16* dst = ws + ((z == 0) ? OFF_XTQ : OFF_XTKV);
    const int id = blockIdx.x;      // 0..511 : b*256 + tile
    const int b  = id >> 8;
    const int t2 = id & 255;
    const int ct = (t2 & 3) * 64;   // channel tile (256/64 = 4)
    const int st = (t2 >> 2) * 64;  // spatial tile (4096/64 = 64)
    const float* sb = src + (size_t)b * 1048576;
    __bf16* db = dst + (size_t)b * 1048576;
    const int l = t & 63;
    const int g = t >> 6;
#pragma unroll
    for (int r = 0; r < 16; ++r) {
      const int c = g * 16 + r;
      lds[c * 66 + l] = (__bf16)sb[(size_t)(ct + c) * 4096 + st + l];
    }
    __syncthreads();
#pragma unroll
    for (int r = 0; r < 16; ++r) {
      const int s = g * 16 + r;
      db[(size_t)(st + s) * 256 + ct + l] = lds[l * 66 + s];
    }
  } else {
    // weights: 4 * 65536 elements, 512 blocks * 512 elements
    const int e0 = blockIdx.x * 512 + t;
#pragma unroll
    for (int p = 0; p < 2; ++p) {
      const int e = e0 + p * 256;
      const int m = e >> 16;
      const int idx = e & 65535;
      const float* w = (m == 0) ? wq : (m == 1) ? wk : (m == 2) ? wv : wo;
      ws[OFF_WQ + (size_t)m * 65536 + idx] = (__bf16)w[idx];
    }
  }
}

// =====================================================================
// proj: z = proj*2+b, proj 0=q,1=k (M=s,N=o), 2=v (M=o,N=s)
// grid (64,1,6) block 256 (4 waves, each 64x64 tile)
// =====================================================================
__global__ __launch_bounds__(256) void proj_kernel(
    const __bf16* __restrict__ wsr, __bf16* __restrict__ wsw,
    const float* __restrict__ bq, const float* __restrict__ bk,
    const float* __restrict__ bv) {
  const int z = blockIdx.z;
  const int proj = z >> 1;
  const int b = z & 1;
  const int t = threadIdx.x;
  const int l = t & 63;
  const int w = t >> 6;
  const int lr = l >> 4, lc = l & 15;
  const int bx = blockIdx.x;

  const __bf16* XT = wsr + ((proj == 0) ? OFF_XTQ : OFF_XTKV) + (size_t)b * 1048576;
  const __bf16* W  = wsr + ((proj == 0) ? OFF_WQ : (proj == 1) ? OFF_WK : OFF_WV);
  const float* bias = (proj == 0) ? bq : (proj == 1) ? bk : bv;

  f32x4 acc[4][4];
#pragma unroll
  for (int i = 0; i < 4; ++i)
#pragma unroll
    for (int j = 0; j < 4; ++j) acc[i][j] = f32x4{0.f, 0.f, 0.f, 0.f};

  if (proj < 2) {
    const int stile = (bx & 31) * 128 + (w & 1) * 64;
    const int otile = (bx >> 5) * 128 + (w >> 1) * 64;
    for (int it = 0; it < 8; ++it) {
      const int c0 = it * 32 + lr * 8;
      s16x8 af[4], bfr[4];
#pragma unroll
      for (int mi = 0; mi < 4; ++mi)
        af[mi] = *(const s16x8*)(XT + (size_t)(stile + mi * 16 + lc) * 256 + c0);
#pragma unroll
      for (int ni = 0; ni < 4; ++ni)
        bfr[ni] = *(const s16x8*)(W + (size_t)(otile + ni * 16 + lc) * 256 + c0);
#pragma unroll
      for (int mi = 0; mi < 4; ++mi)
#pragma unroll
        for (int ni = 0; ni < 4; ++ni)
          acc[mi][ni] = MFMA_BF16(af[mi], bfr[ni], acc[mi][ni]);
    }
    const float scale = (proj == 0) ? 0.125f : 1.0f;
    __bf16* dst = wsw + ((proj == 0) ? OFF_Q : OFF_K);
#pragma unroll
    for (int ni = 0; ni < 4; ++ni) {
      const int o = otile + ni * 16 + lc;
      const float bb = bias[o];
      const int n = o >> 6, d = o & 63;
#pragma unroll
      for (int mi = 0; mi < 4; ++mi)
#pragma unroll
        for (int r = 0; r < 4; ++r) {
          const int s = stile + mi * 16 + lr * 4 + r;
          dst[((size_t)(b * 4 + n) * 4096 + s) * 64 + d] =
              (__bf16)((acc[mi][ni][r] + bb) * scale);
        }
    }
  } else {
    const int otile = (bx & 1) * 128 + (w & 1) * 64;
    const int stile = (bx >> 1) * 128 + (w >> 1) * 64;
    for (int it = 0; it < 8; ++it) {
      const int c0 = it * 32 + lr * 8;
      s16x8 af[4], bfr[4];
#pragma unroll
      for (int mi = 0; mi < 4; ++mi)
        af[mi] = *(const s16x8*)(W + (size_t)(otile + mi * 16 + lc) * 256 + c0);
#pragma unroll
      for (int ni = 0; ni < 4; ++ni)
        bfr[ni] = *(const s16x8*)(XT + (size_t)(stile + ni * 16 + lc) * 256 + c0);
#pragma unroll
      for (int mi = 0; mi < 4; ++mi)
#pragma unroll
        for (int ni = 0; ni < 4; ++ni)
          acc[mi][ni] = MFMA_BF16(af[mi], bfr[ni], acc[mi][ni]);
    }
    __bf16* dst = wsw + OFF_V;
#pragma unroll
    for (int mi = 0; mi < 4; ++mi)
#pragma unroll
      for (int r = 0; r < 4; ++r) {
        const int o = otile + mi * 16 + lr * 4 + r;
        const float bb = bias[o];
        const int n = o >> 6, d = o & 63;
#pragma unroll
        for (int ni = 0; ni < 4; ++ni) {
          const int s = stile + ni * 16 + lc;
          dst[((size_t)(b * 4 + n) * 64 + d) * 4096 + s] = (__bf16)(acc[mi][ni][r] + bb);
        }
      }
  }
}

// =====================================================================
// attn: flash attention. grid (64, 8) block 256. 4 waves x 16 q-rows.
// Q,K in [s][64] bf16 (Q pre-scaled), V in [64][s].
// =====================================================================
#define KPAD 72  // 64 + 8 bf16 pad -> 144B row stride, conflict-light b128 reads

__global__ __launch_bounds__(256) void attn_kernel(
    const __bf16* __restrict__ wsr, __bf16* __restrict__ wsw) {
  __shared__ __align__(16) __bf16 Kt[64 * KPAD];
  __shared__ __align__(16) __bf16 Vt[64 * KPAD];
  __shared__ __align__(16) __bf16 Pt[4 * 16 * KPAD];

  const int t = threadIdx.x;
  const int l = t & 63;
  const int w = t >> 6;
  const int lr = l >> 4, lc = l & 15;
  const int bh = blockIdx.y;                 // b*4 + n
  const int qbase = blockIdx.x * 64;

  const __bf16* Q = wsr + OFF_Q + (size_t)bh * (4096 * 64);
  const __bf16* K = wsr + OFF_K + (size_t)bh * (4096 * 64);
  const __bf16* V = wsr + OFF_V + (size_t)bh * (64 * 4096);

  // Q fragments for this wave's 16 rows (A: row=l&15, k=(l>>4)*8+j)
  s16x8 aq[2];
#pragma unroll
  for (int kb = 0; kb < 2; ++kb)
    aq[kb] = *(const s16x8*)(Q + (size_t)(qbase + w * 16 + lc) * 64 + kb * 32 + lr * 8);

  f32x4 o4[4];
#pragma unroll
  for (int i = 0; i < 4; ++i) o4[i] = f32x4{0.f, 0.f, 0.f, 0.f};
  float m[4], lsum[4];
#pragma unroll
  for (int r = 0; r < 4; ++r) { m[r] = -1e30f; lsum[r] = 0.f; }

  __bf16* Pw = Pt + w * 16 * KPAD;

#pragma unroll 1
  for (int jb = 0; jb < 4096; jb += 64) {
    // stage K tile [64 j][64 d] and V tile [64 d][64 j] (padded rows)
#pragma unroll
    for (int p = 0; p < 2; ++p) {
      const int id = p * 256 + t;
      const int row = id >> 3, ch = id & 7;
      *(s16x8*)(Kt + row * KPAD + ch * 8) =
          *(const s16x8*)(K + (size_t)(jb + row) * 64 + ch * 8);
      *(s16x8*)(Vt + row * KPAD + ch * 8) =
          *(const s16x8*)(V + (size_t)row * 4096 + jb + ch * 8);
    }
    __syncthreads();

    // logits: 4 j-subtiles of 16
    f32x4 s4[4];
#pragma unroll
    for (int jt = 0; jt < 4; ++jt) {
      f32x4 a = f32x4{0.f, 0.f, 0.f, 0.f};
#pragma unroll
      for (int kb = 0; kb < 2; ++kb) {
        s16x8 bk = *(const s16x8*)(Kt + (jt * 16 + lc) * KPAD + kb * 32 + lr * 8);
        a = MFMA_BF16(aq[kb], bk, a);
      }
      s4[jt] = a;
    }

    // online softmax (row i = lr*4 + r; cols across lanes lc)
    float f[4], rs[4];
#pragma unroll
    for (int r = 0; r < 4; ++r) {
      float v = fmaxf(fmaxf(s4[0][r], s4[1][r]), fmaxf(s4[2][r], s4[3][r]));
      v = fmaxf(v, __shfl_xor(v, 1));
      v = fmaxf(v, __shfl_xor(v, 2));
      v = fmaxf(v, __shfl_xor(v, 4));
      v = fmaxf(v, __shfl_xor(v, 8));
      const float mn = fmaxf(m[r], v);
      f[r] = __expf(m[r] - mn);
      m[r] = mn;
      rs[r] = 0.f;
    }
#pragma unroll
    for (int jt = 0; jt < 4; ++jt) {
      const int j = jt * 16 + lc;
#pragma unroll
      for (int r = 0; r < 4; ++r) {
        const float p = __expf(s4[jt][r] - m[r]);
        rs[r] += p;
        Pw[(lr * 4 + r) * KPAD + j] = (__bf16)p;
      }
    }
#pragma unroll
    for (int r = 0; r < 4; ++r) {
      float v = rs[r];
      v += __shfl_xor(v, 1);
      v += __shfl_xor(v, 2);
      v += __shfl_xor(v, 4);
      v += __shfl_xor(v, 8);
      lsum[r] = lsum[r] * f[r] + v;
    }
#pragma unroll
    for (int nt = 0; nt < 4; ++nt)
#pragma unroll
      for (int r = 0; r < 4; ++r) o4[nt][r] *= f[r];

    // PV: A = P[16 x 64] from LDS, B = V tile
#pragma unroll
    for (int kb = 0; kb < 2; ++kb) {
      s16x8 pa = *(const s16x8*)(Pw + lc * KPAD + kb * 32 + lr * 8);
#pragma unroll
      for (int nt = 0; nt < 4; ++nt) {
        s16x8 bv = *(const s16x8*)(Vt + (nt * 16 + lc) * KPAD + kb * 32 + lr * 8);
        o4[nt] = MFMA_BF16(pa, bv, o4[nt]);
      }
    }
    __syncthreads();
  }

  // epilogue: normalize, write attnout [b][s][c] bf16
  const int b = bh >> 2, n = bh & 3;
  __bf16* AO = wsw + OFF_AO + (size_t)b * (4096 * 256);
#pragma unroll
  for (int r = 0; r < 4; ++r) {
    const float inv = 1.0f / lsum[r];
    const int s = qbase + w * 16 + lr * 4 + r;
#pragma unroll
    for (int nt = 0; nt < 4; ++nt)
      AO[(size_t)s * 256 + n * 64 + nt * 16 + lc] = (__bf16)(o4[nt][r] * inv);
  }
}

// =====================================================================
// outproj: out[b][o][s] = Wo . AO^T + bo   grid (64, 2) block 256
// =====================================================================
__global__ __launch_bounds__(256) void outproj_kernel(
    const __bf16* __restrict__ wsr, const float* __restrict__ bo,
    float* __restrict__ out) {
  const int b = blockIdx.y;
  const int bx = blockIdx.x;
  const int t = threadIdx.x;
  const int l = t & 63;
  const int w = t >> 6;
  const int lr = l >> 4, lc = l & 15;
  const int otile = (bx & 1) * 128 + (w & 1) * 64;
  const int stile = (bx >> 1) * 128 + (w >> 1) * 64;
  const __bf16* Wo = wsr + OFF_WO;
  const __bf16* AO = wsr + OFF_AO + (size_t)b * 1048576;

  f32x4 acc[4][4];
#pragma unroll
  for (int i = 0; i < 4; ++i)
#pragma unroll
    for (int j = 0; j < 4; ++j) acc[i][j] = f32x4{0.f, 0.f, 0.f, 0.f};

  for (int it = 0; it < 8; ++it) {
    const int c0 = it * 32 + lr * 8;
    s16x8 af[4], bfr[4];
#pragma unroll
    for (int mi = 0; mi < 4; ++mi)
      af[mi] = *(const s16x8*)(Wo + (size_t)(otile + mi * 16 + lc) * 256 + c0);
#pragma unroll
    for (int ni = 0; ni < 4; ++ni)
      bfr[ni] = *(const s16x8*)(AO + (size_t)(stile + ni * 16 + lc) * 256 + c0);
#pragma unroll
    for (int mi = 0; mi < 4; ++mi)
#pragma unroll
      for (int ni = 0; ni < 4; ++ni)
        acc[mi][ni] = MFMA_BF16(af[mi], bfr[ni], acc[mi][ni]);
  }
#pragma unroll
  for (int mi = 0; mi < 4; ++mi)
#pragma unroll
    for (int r = 0; r < 4; ++r) {
      const int o = otile + mi * 16 + lr * 4 + r;
      const float bb = bo[o];
#pragma unroll
      for (int ni = 0; ni < 4; ++ni) {
        const int s = stile + ni * 16 + lc;
        out[((size_t)b * 256 + o) * 4096 + s] = acc[mi][ni][r] + bb;
      }
    }
}

// =====================================================================
extern "C" void kernel_launch(void* const* d_in, const int* in_sizes, int n_in,
                              void* d_out, int out_size, void* d_ws, size_t ws_size,
                              hipStream_t stream) {
  const float* xq  = (const float*)d_in[0];
  const float* xkv = (const float*)d_in[1];
  const float* wq  = (const float*)d_in[2];
  const float* bq  = (const float*)d_in[3];
  const float* wk  = (const float*)d_in[4];
  const float* bk  = (const float*)d_in[5];
  const float* wv  = (const float*)d_in[6];
  const float* bv  = (const float*)d_in[7];
  const float* wo  = (const float*)d_in[8];
  const float* bo  = (const float*)d_in[9];
  __bf16* ws = (__bf16*)d_ws;
  float* out = (float*)d_out;

  prep_kernel<<<dim3(512, 1, 3), 256, 0, stream>>>(xq, xkv, wq, wk, wv, wo, ws);
  proj_kernel<<<dim3(64, 1, 6), 256, 0, stream>>>(ws, ws, bq, bk, bv);
  attn_kernel<<<dim3(64, 8), 256, 0, stream>>>(ws, ws);
  outproj_kernel<<<dim3(64, 2), 256, 0, stream>>>(ws, bo, out);
}

// Round 3
// 219.829 us; speedup vs baseline: 1.1192x; 1.1192x over previous
//
#include <hip/hip_runtime.h>
#include <hip/hip_bf16.h>
#include <type_traits>
#include <cstdint>

typedef float  f32x4  __attribute__((ext_vector_type(4)));
typedef short  s16x8  __attribute__((ext_vector_type(8)));
typedef __bf16 bf16x8 __attribute__((ext_vector_type(8)));

// ---- MFMA wrapper: tolerant to builtin taking v8i16 or v8bf16 ----
template <typename V>
__device__ static inline auto mfma_try(V a, V b, f32x4 c, int)
    -> decltype(__builtin_amdgcn_mfma_f32_16x16x32_bf16(a, b, c, 0, 0, 0)) {
  return __builtin_amdgcn_mfma_f32_16x16x32_bf16(a, b, c, 0, 0, 0);
}
template <typename V>
__device__ static inline f32x4 mfma_try(V a, V b, f32x4 c, long) {
  return __builtin_amdgcn_mfma_f32_16x16x32_bf16(
      __builtin_bit_cast(bf16x8, a), __builtin_bit_cast(bf16x8, b), c, 0, 0, 0);
}
__device__ static inline f32x4 MFMA_BF16(s16x8 a, s16x8 b, f32x4 c) {
  return mfma_try(a, b, c, 0);
}

// ---- workspace layout (bf16 element offsets) ----
static constexpr size_t OFF_XTQ  = 0;         // [2][4096][256]
static constexpr size_t OFF_XTKV = 2097152;   // [2][4096][256]
static constexpr size_t OFF_WQ   = 4194304;   // [256][256]
static constexpr size_t OFF_WK   = 4259840;
static constexpr size_t OFF_WV   = 4325376;
static constexpr size_t OFF_WO   = 4390912;
static constexpr size_t OFF_Q    = 4456448;   // [2][4][4096][64]  (pre-scaled by 1/8)
static constexpr size_t OFF_K    = 6553600;   // [2][4][4096][64]
static constexpr size_t OFF_V    = 8650752;   // [2][4][64][4096]
static constexpr size_t OFF_AO   = 10747904;  // [2][4096][256]

// =====================================================================
// prep: transpose+cvt x_q/x_kv [C][S]f32 -> [S][C]bf16 ; cvt weights
// grid (512,1,3) block 256
// =====================================================================
__global__ __launch_bounds__(256) void prep_kernel(
    const float* __restrict__ xq, const float* __restrict__ xkv,
    const float* __restrict__ wq, const float* __restrict__ wk,
    const float* __restrict__ wv, const float* __restrict__ wo,
    __bf16* __restrict__ ws) {
  __shared__ __bf16 lds[64 * 66];
  const int t = threadIdx.x;
  const int z = blockIdx.z;
  if (z < 2) {
    const float* src = (z == 0) ? xq : xkv;
    __bf16* dst = ws + ((z == 0) ? OFF_XTQ : OFF_XTKV);
    const int id = blockIdx.x;      // 0..511 : b*256 + tile
    const int b  = id >> 8;
    const int t2 = id & 255;
    const int ct = (t2 & 3) * 64;   // channel tile (256/64 = 4)
    const int st = (t2 >> 2) * 64;  // spatial tile (4096/64 = 64)
    const float* sb = src + (size_t)b * 1048576;
    __bf16* db = dst + (size_t)b * 1048576;
    const int l = t & 63;
    const int g = t >> 6;
#pragma unroll
    for (int r = 0; r < 16; ++r) {
      const int c = g * 16 + r;
      lds[c * 66 + l] = (__bf16)sb[(size_t)(ct + c) * 4096 + st + l];
    }
    __syncthreads();
#pragma unroll
    for (int r = 0; r < 16; ++r) {
      const int s = g * 16 + r;
      db[(size_t)(st + s) * 256 + ct + l] = lds[l * 66 + s];
    }
  } else {
    // weights: 4 * 65536 elements, 512 blocks * 512 elements
    const int e0 = blockIdx.x * 512 + t;
#pragma unroll
    for (int p = 0; p < 2; ++p) {
      const int e = e0 + p * 256;
      const int m = e >> 16;
      const int idx = e & 65535;
      const float* w = (m == 0) ? wq : (m == 1) ? wk : (m == 2) ? wv : wo;
      ws[OFF_WQ + (size_t)m * 65536 + idx] = (__bf16)w[idx];
    }
  }
}

// =====================================================================
// proj: z = proj*2+b, proj 0=q,1=k (M=s,N=o), 2=v (M=o,N=s)
// grid (128,1,6) block 256; wave-tile 32x64
// =====================================================================
__global__ __launch_bounds__(256) void proj_kernel(
    const __bf16* __restrict__ wsr, __bf16* __restrict__ wsw,
    const float* __restrict__ bq, const float* __restrict__ bk,
    const float* __restrict__ bv) {
  const int z = blockIdx.z;
  const int proj = z >> 1;
  const int b = z & 1;
  const int t = threadIdx.x;
  const int l = t & 63;
  const int w = t >> 6;
  const int lr = l >> 4, lc = l & 15;
  const int bx = blockIdx.x;

  const __bf16* XT = wsr + ((proj == 0) ? OFF_XTQ : OFF_XTKV) + (size_t)b * 1048576;
  const __bf16* W  = wsr + ((proj == 0) ? OFF_WQ : (proj == 1) ? OFF_WK : OFF_WV);
  const float* bias = (proj == 0) ? bq : (proj == 1) ? bk : bv;

  if (proj < 2) {
    // s-major: wave covers 32 s x 64 o
    const int stile = (bx >> 2) * 128 + w * 32;
    const int otile = (bx & 3) * 64;
    f32x4 acc[2][4];
#pragma unroll
    for (int i = 0; i < 2; ++i)
#pragma unroll
      for (int j = 0; j < 4; ++j) acc[i][j] = f32x4{0.f, 0.f, 0.f, 0.f};
    for (int it = 0; it < 8; ++it) {
      const int c0 = it * 32 + lr * 8;
      s16x8 af[2], bfr[4];
#pragma unroll
      for (int mi = 0; mi < 2; ++mi)
        af[mi] = *(const s16x8*)(XT + (size_t)(stile + mi * 16 + lc) * 256 + c0);
#pragma unroll
      for (int ni = 0; ni < 4; ++ni)
        bfr[ni] = *(const s16x8*)(W + (size_t)(otile + ni * 16 + lc) * 256 + c0);
#pragma unroll
      for (int mi = 0; mi < 2; ++mi)
#pragma unroll
        for (int ni = 0; ni < 4; ++ni)
          acc[mi][ni] = MFMA_BF16(af[mi], bfr[ni], acc[mi][ni]);
    }
    const float scale = (proj == 0) ? 0.125f : 1.0f;
    __bf16* dst = wsw + ((proj == 0) ? OFF_Q : OFF_K);
#pragma unroll
    for (int ni = 0; ni < 4; ++ni) {
      const int o = otile + ni * 16 + lc;
      const float bb = bias[o];
      const int n = o >> 6, d = o & 63;
#pragma unroll
      for (int mi = 0; mi < 2; ++mi)
#pragma unroll
        for (int r = 0; r < 4; ++r) {
          const int s = stile + mi * 16 + lr * 4 + r;
          dst[((size_t)(b * 4 + n) * 4096 + s) * 64 + d] =
              (__bf16)((acc[mi][ni][r] + bb) * scale);
        }
    }
  } else {
    // V: wave covers 64 o x 32 s
    const int otile = (bx & 3) * 64;
    const int stile = (bx >> 2) * 128 + w * 32;
    f32x4 acc[4][2];
#pragma unroll
    for (int i = 0; i < 4; ++i)
#pragma unroll
      for (int j = 0; j < 2; ++j) acc[i][j] = f32x4{0.f, 0.f, 0.f, 0.f};
    for (int it = 0; it < 8; ++it) {
      const int c0 = it * 32 + lr * 8;
      s16x8 af[4], bfr[2];
#pragma unroll
      for (int mi = 0; mi < 4; ++mi)
        af[mi] = *(const s16x8*)(W + (size_t)(otile + mi * 16 + lc) * 256 + c0);
#pragma unroll
      for (int ni = 0; ni < 2; ++ni)
        bfr[ni] = *(const s16x8*)(XT + (size_t)(stile + ni * 16 + lc) * 256 + c0);
#pragma unroll
      for (int mi = 0; mi < 4; ++mi)
#pragma unroll
        for (int ni = 0; ni < 2; ++ni)
          acc[mi][ni] = MFMA_BF16(af[mi], bfr[ni], acc[mi][ni]);
    }
    __bf16* dst = wsw + OFF_V;
#pragma unroll
    for (int mi = 0; mi < 4; ++mi)
#pragma unroll
      for (int r = 0; r < 4; ++r) {
        const int o = otile + mi * 16 + lr * 4 + r;
        const float bb = bias[o];
        const int n = o >> 6, d = o & 63;
#pragma unroll
        for (int ni = 0; ni < 2; ++ni) {
          const int s = stile + ni * 16 + lc;
          dst[((size_t)(b * 4 + n) * 64 + d) * 4096 + s] = (__bf16)(acc[mi][ni][r] + bb);
        }
      }
  }
}

// =====================================================================
// attn: flash attention. grid (64, 8) block 512 (8 waves).
// Waves 0-3: even 64-wide j-tiles; waves 4-7: odd tiles. LDS merge at end.
// Q,K in [s][64] bf16 (Q pre-scaled), V in [64][s].
// =====================================================================
#define KPAD 72  // 64 + 8 bf16 pad -> 144B row stride

__global__ __launch_bounds__(512) void attn_kernel(
    const __bf16* __restrict__ wsr, __bf16* __restrict__ wsw) {
  __shared__ __align__(16) __bf16 Kt[2][64 * KPAD];
  __shared__ __align__(16) __bf16 Vt[2][64 * KPAD];
  __shared__ __align__(16) __bf16 Pt[8][16 * KPAD];
  __shared__ float Mg[4][16][68];   // merge buffer: o(64) + m + l

  const int t = threadIdx.x;        // 0..511
  const int l = t & 63;
  const int w = t >> 6;             // 0..7
  const int g = w >> 2;             // j-parity group
  const int wq = w & 3;             // q-row subtile
  const int lr = l >> 4, lc = l & 15;
  const int bh = blockIdx.y;        // b*4 + n
  const int qbase = blockIdx.x * 64;

  const __bf16* Q = wsr + OFF_Q + (size_t)bh * (4096 * 64);
  const __bf16* K = wsr + OFF_K + (size_t)bh * (4096 * 64);
  const __bf16* V = wsr + OFF_V + (size_t)bh * (64 * 4096);

  // Q fragments for this wave's 16 rows (A: row=l&15, k=(l>>4)*8+j)
  s16x8 aq[2];
#pragma unroll
  for (int kb = 0; kb < 2; ++kb)
    aq[kb] = *(const s16x8*)(Q + (size_t)(qbase + wq * 16 + lc) * 64 + kb * 32 + lr * 8);

  f32x4 o4[4];
#pragma unroll
  for (int i = 0; i < 4; ++i) o4[i] = f32x4{0.f, 0.f, 0.f, 0.f};
  float m[4], lsum[4];
#pragma unroll
  for (int r = 0; r < 4; ++r) { m[r] = -1e30f; lsum[r] = 0.f; }

  __bf16* Pw = Pt[w];

  // staging: ids 0..1023 cover 2 tiles x 64 rows x 8 chunks (16B each)
  s16x8 pk[2], pv[2];
#pragma unroll
  for (int p = 0; p < 2; ++p) {
    const int id = p * 512 + t;
    const int tg = id >> 9, row = (id >> 3) & 63, ch = id & 7;
    const int jbg = tg * 64;
    pk[p] = *(const s16x8*)(K + (size_t)(jbg + row) * 64 + ch * 8);
    pv[p] = *(const s16x8*)(V + (size_t)row * 4096 + jbg + ch * 8);
  }

#pragma unroll 1
  for (int it = 0; it < 32; ++it) {
    __syncthreads();   // previous iteration's readers done
#pragma unroll
    for (int p = 0; p < 2; ++p) {
      const int id = p * 512 + t;
      const int tg = id >> 9, row = (id >> 3) & 63, ch = id & 7;
      *(s16x8*)(Kt[tg] + row * KPAD + ch * 8) = pk[p];
      *(s16x8*)(Vt[tg] + row * KPAD + ch * 8) = pv[p];
    }
    if (it + 1 < 32) {
#pragma unroll
      for (int p = 0; p < 2; ++p) {
        const int id = p * 512 + t;
        const int tg = id >> 9, row = (id >> 3) & 63, ch = id & 7;
        const int jbg = (it + 1) * 128 + tg * 64;
        pk[p] = *(const s16x8*)(K + (size_t)(jbg + row) * 64 + ch * 8);
        pv[p] = *(const s16x8*)(V + (size_t)row * 4096 + jbg + ch * 8);
      }
    }
    __syncthreads();   // this iteration's tiles ready

    // logits: 4 j-subtiles of 16 from this group's tile
    f32x4 s4[4];
#pragma unroll
    for (int jt = 0; jt < 4; ++jt) {
      f32x4 a = f32x4{0.f, 0.f, 0.f, 0.f};
#pragma unroll
      for (int kb = 0; kb < 2; ++kb) {
        s16x8 bk = *(const s16x8*)(Kt[g] + (jt * 16 + lc) * KPAD + kb * 32 + lr * 8);
        a = MFMA_BF16(aq[kb], bk, a);
      }
      s4[jt] = a;
    }

    // online softmax (row i = lr*4 + r; cols across lanes lc)
    float f[4], rs[4];
#pragma unroll
    for (int r = 0; r < 4; ++r) {
      float v = fmaxf(fmaxf(s4[0][r], s4[1][r]), fmaxf(s4[2][r], s4[3][r]));
      v = fmaxf(v, __shfl_xor(v, 1));
      v = fmaxf(v, __shfl_xor(v, 2));
      v = fmaxf(v, __shfl_xor(v, 4));
      v = fmaxf(v, __shfl_xor(v, 8));
      const float mn = fmaxf(m[r], v);
      f[r] = __expf(m[r] - mn);
      m[r] = mn;
      rs[r] = 0.f;
    }
#pragma unroll
    for (int jt = 0; jt < 4; ++jt) {
      const int j = jt * 16 + lc;
#pragma unroll
      for (int r = 0; r < 4; ++r) {
        const float p = __expf(s4[jt][r] - m[r]);
        rs[r] += p;
        Pw[(lr * 4 + r) * KPAD + j] = (__bf16)p;
      }
    }
#pragma unroll
    for (int r = 0; r < 4; ++r) {
      float v = rs[r];
      v += __shfl_xor(v, 1);
      v += __shfl_xor(v, 2);
      v += __shfl_xor(v, 4);
      v += __shfl_xor(v, 8);
      lsum[r] = lsum[r] * f[r] + v;
    }
#pragma unroll
    for (int nt = 0; nt < 4; ++nt)
#pragma unroll
      for (int r = 0; r < 4; ++r) o4[nt][r] *= f[r];

    // PV: A = P[16 x 64] from LDS, B = V tile
#pragma unroll
    for (int kb = 0; kb < 2; ++kb) {
      s16x8 pa = *(const s16x8*)(Pw + lc * KPAD + kb * 32 + lr * 8);
#pragma unroll
      for (int nt = 0; nt < 4; ++nt) {
        s16x8 bv = *(const s16x8*)(Vt[g] + (nt * 16 + lc) * KPAD + kb * 32 + lr * 8);
        o4[nt] = MFMA_BF16(pa, bv, o4[nt]);
      }
    }
  }

  // merge the two j-groups through LDS, then write AO
  if (g == 1) {
#pragma unroll
    for (int nt = 0; nt < 4; ++nt)
#pragma unroll
      for (int r = 0; r < 4; ++r)
        Mg[wq][lr * 4 + r][nt * 16 + lc] = o4[nt][r];
    if (lc == 0) {
#pragma unroll
      for (int r = 0; r < 4; ++r) {
        Mg[wq][lr * 4 + r][64] = m[r];
        Mg[wq][lr * 4 + r][65] = lsum[r];
      }
    }
  }
  __syncthreads();
  if (g == 0) {
    const int b = bh >> 2, n = bh & 3;
    __bf16* AO = wsw + OFF_AO + (size_t)b * (4096 * 256);
#pragma unroll
    for (int r = 0; r < 4; ++r) {
      const int row = lr * 4 + r;
      const float m2 = Mg[wq][row][64];
      const float l2 = Mg[wq][row][65];
      const float M = fmaxf(m[r], m2);
      const float f1 = __expf(m[r] - M);
      const float f2 = __expf(m2 - M);
      const float linv = 1.0f / (lsum[r] * f1 + l2 * f2);
      const int s = qbase + wq * 16 + row;
#pragma unroll
      for (int nt = 0; nt < 4; ++nt) {
        const float val = (o4[nt][r] * f1 + Mg[wq][row][nt * 16 + lc] * f2) * linv;
        AO[(size_t)s * 256 + n * 64 + nt * 16 + lc] = (__bf16)val;
      }
    }
  }
}

// =====================================================================
// outproj: out[b][o][s] = Wo . AO^T + bo   grid (128, 2) block 256
// wave-tile 32(o) x 64(s)
// =====================================================================
__global__ __launch_bounds__(256) void outproj_kernel(
    const __bf16* __restrict__ wsr, const float* __restrict__ bo,
    float* __restrict__ out) {
  const int b = blockIdx.y;
  const int bx = blockIdx.x;
  const int t = threadIdx.x;
  const int l = t & 63;
  const int w = t >> 6;
  const int lr = l >> 4, lc = l & 15;
  const int otile = (bx & 1) * 128 + w * 32;
  const int stile = (bx >> 1) * 64;
  const __bf16* Wo = wsr + OFF_WO;
  const __bf16* AO = wsr + OFF_AO + (size_t)b * 1048576;

  f32x4 acc[2][4];
#pragma unroll
  for (int i = 0; i < 2; ++i)
#pragma unroll
    for (int j = 0; j < 4; ++j) acc[i][j] = f32x4{0.f, 0.f, 0.f, 0.f};

  for (int it = 0; it < 8; ++it) {
    const int c0 = it * 32 + lr * 8;
    s16x8 af[2], bfr[4];
#pragma unroll
    for (int mi = 0; mi < 2; ++mi)
      af[mi] = *(const s16x8*)(Wo + (size_t)(otile + mi * 16 + lc) * 256 + c0);
#pragma unroll
    for (int ni = 0; ni < 4; ++ni)
      bfr[ni] = *(const s16x8*)(AO + (size_t)(stile + ni * 16 + lc) * 256 + c0);
#pragma unroll
    for (int mi = 0; mi < 2; ++mi)
#pragma unroll
      for (int ni = 0; ni < 4; ++ni)
        acc[mi][ni] = MFMA_BF16(af[mi], bfr[ni], acc[mi][ni]);
  }
#pragma unroll
  for (int mi = 0; mi < 2; ++mi)
#pragma unroll
    for (int r = 0; r < 4; ++r) {
      const int o = otile + mi * 16 + lr * 4 + r;
      const float bb = bo[o];
#pragma unroll
      for (int ni = 0; ni < 4; ++ni) {
        const int s = stile + ni * 16 + lc;
        out[((size_t)b * 256 + o) * 4096 + s] = acc[mi][ni][r] + bb;
      }
    }
}

// =====================================================================
extern "C" void kernel_launch(void* const* d_in, const int* in_sizes, int n_in,
                              void* d_out, int out_size, void* d_ws, size_t ws_size,
                              hipStream_t stream) {
  const float* xq  = (const float*)d_in[0];
  const float* xkv = (const float*)d_in[1];
  const float* wq  = (const float*)d_in[2];
  const float* bq  = (const float*)d_in[3];
  const float* wk  = (const float*)d_in[4];
  const float* bk  = (const float*)d_in[5];
  const float* wv  = (const float*)d_in[6];
  const float* bv  = (const float*)d_in[7];
  const float* wo  = (const float*)d_in[8];
  const float* bo  = (const float*)d_in[9];
  __bf16* ws = (__bf16*)d_ws;
  float* out = (float*)d_out;

  prep_kernel<<<dim3(512, 1, 3), 256, 0, stream>>>(xq, xkv, wq, wk, wv, wo, ws);
  proj_kernel<<<dim3(128, 1, 6), 256, 0, stream>>>(ws, ws, bq, bk, bv);
  attn_kernel<<<dim3(64, 8), 512, 0, stream>>>(ws, ws);
  outproj_kernel<<<dim3(128, 2), 256, 0, stream>>>(ws, bo, out);
}

// Round 7
// 168.395 us; speedup vs baseline: 1.4611x; 1.3054x over previous
//
#include <hip/hip_runtime.h>
#include <hip/hip_bf16.h>
#include <type_traits>
#include <cstdint>

typedef float  f32x4  __attribute__((ext_vector_type(4)));
typedef short  s16x8  __attribute__((ext_vector_type(8)));
typedef __bf16 bf16x8 __attribute__((ext_vector_type(8)));

#if __has_builtin(__builtin_amdgcn_exp2f)
#define EXP2(x) __builtin_amdgcn_exp2f(x)
#else
#define EXP2(x) exp2f(x)
#endif

// ---- MFMA wrapper: tolerant to builtin taking v8i16 or v8bf16 ----
template <typename V>
__device__ static inline auto mfma_try(V a, V b, f32x4 c, int)
    -> decltype(__builtin_amdgcn_mfma_f32_16x16x32_bf16(a, b, c, 0, 0, 0)) {
  return __builtin_amdgcn_mfma_f32_16x16x32_bf16(a, b, c, 0, 0, 0);
}
template <typename V>
__device__ static inline f32x4 mfma_try(V a, V b, f32x4 c, long) {
  return __builtin_amdgcn_mfma_f32_16x16x32_bf16(
      __builtin_bit_cast(bf16x8, a), __builtin_bit_cast(bf16x8, b), c, 0, 0, 0);
}
__device__ static inline f32x4 MFMA_BF16(s16x8 a, s16x8 b, f32x4 c) {
  return mfma_try(a, b, c, 0);
}

// ---- workspace layout (bf16 element offsets) ----
static constexpr size_t OFF_XTQ  = 0;         // [2][4096][256]
static constexpr size_t OFF_XTKV = 2097152;   // [2][4096][256]
static constexpr size_t OFF_WQ   = 4194304;   // [256][256]
static constexpr size_t OFF_WK   = 4259840;
static constexpr size_t OFF_WV   = 4325376;
static constexpr size_t OFF_WO   = 4390912;
static constexpr size_t OFF_Q    = 4456448;   // [2][4][4096][64]  (pre-scaled by 0.125*log2e)
static constexpr size_t OFF_K    = 6553600;   // [2][4][4096][64]
static constexpr size_t OFF_V    = 8650752;   // [2][4][64][4096]
static constexpr size_t OFF_AO   = 10747904;  // [2][4096][256]

// =====================================================================
// prep: transpose+cvt x_q/x_kv [C][S]f32 -> [S][C]bf16 ; cvt weights
// =====================================================================
__global__ __launch_bounds__(256) void prep_kernel(
    const float* __restrict__ xq, const float* __restrict__ xkv,
    const float* __restrict__ wq, const float* __restrict__ wk,
    const float* __restrict__ wv, const float* __restrict__ wo,
    __bf16* __restrict__ ws) {
  __shared__ __bf16 lds[64 * 66];
  const int t = threadIdx.x;
  const int z = blockIdx.z;
  if (z < 2) {
    const float* src = (z == 0) ? xq : xkv;
    __bf16* dst = ws + ((z == 0) ? OFF_XTQ : OFF_XTKV);
    const int id = blockIdx.x;
    const int b  = id >> 8;
    const int t2 = id & 255;
    const int ct = (t2 & 3) * 64;
    const int st = (t2 >> 2) * 64;
    const float* sb = src + (size_t)b * 1048576;
    __bf16* db = dst + (size_t)b * 1048576;
    const int l = t & 63;
    const int g = t >> 6;
#pragma unroll
    for (int r = 0; r < 16; ++r) {
      const int c = g * 16 + r;
      lds[c * 66 + l] = (__bf16)sb[(size_t)(ct + c) * 4096 + st + l];
    }
    __syncthreads();
#pragma unroll
    for (int r = 0; r < 16; ++r) {
      const int s = g * 16 + r;
      db[(size_t)(st + s) * 256 + ct + l] = lds[l * 66 + s];
    }
  } else {
    const int e0 = blockIdx.x * 512 + t;
#pragma unroll
    for (int p = 0; p < 2; ++p) {
      const int e = e0 + p * 256;
      const int m = e >> 16;
      const int idx = e & 65535;
      const float* w = (m == 0) ? wq : (m == 1) ? wk : (m == 2) ? wv : wo;
      ws[OFF_WQ + (size_t)m * 65536 + idx] = (__bf16)w[idx];
    }
  }
}

// =====================================================================
// proj: z = proj*2+b, proj 0=q,1=k (M=s,N=o), 2=v (M=o,N=s)
// grid (128,1,6) block 256; wave-tile 32x64
// =====================================================================
__global__ __launch_bounds__(256) void proj_kernel(
    const __bf16* __restrict__ wsr, __bf16* __restrict__ wsw,
    const float* __restrict__ bq, const float* __restrict__ bk,
    const float* __restrict__ bv) {
  const int z = blockIdx.z;
  const int proj = z >> 1;
  const int b = z & 1;
  const int t = threadIdx.x;
  const int l = t & 63;
  const int w = t >> 6;
  const int lr = l >> 4, lc = l & 15;
  const int bx = blockIdx.x;

  const __bf16* XT = wsr + ((proj == 0) ? OFF_XTQ : OFF_XTKV) + (size_t)b * 1048576;
  const __bf16* W  = wsr + ((proj == 0) ? OFF_WQ : (proj == 1) ? OFF_WK : OFF_WV);
  const float* bias = (proj == 0) ? bq : (proj == 1) ? bk : bv;

  if (proj < 2) {
    const int stile = (bx >> 2) * 128 + w * 32;
    const int otile = (bx & 3) * 64;
    f32x4 acc[2][4];
#pragma unroll
    for (int i = 0; i < 2; ++i)
#pragma unroll
      for (int j = 0; j < 4; ++j) acc[i][j] = f32x4{0.f, 0.f, 0.f, 0.f};
    for (int it = 0; it < 8; ++it) {
      const int c0 = it * 32 + lr * 8;
      s16x8 af[2], bfr[4];
#pragma unroll
      for (int mi = 0; mi < 2; ++mi)
        af[mi] = *(const s16x8*)(XT + (size_t)(stile + mi * 16 + lc) * 256 + c0);
#pragma unroll
      for (int ni = 0; ni < 4; ++ni)
        bfr[ni] = *(const s16x8*)(W + (size_t)(otile + ni * 16 + lc) * 256 + c0);
#pragma unroll
      for (int mi = 0; mi < 2; ++mi)
#pragma unroll
        for (int ni = 0; ni < 4; ++ni)
          acc[mi][ni] = MFMA_BF16(af[mi], bfr[ni], acc[mi][ni]);
    }
    // Q carries attn scale AND log2(e) so attn can use exp2 directly
    const float scale = (proj == 0) ? 0.125f * 1.44269504088896f : 1.0f;
    __bf16* dst = wsw + ((proj == 0) ? OFF_Q : OFF_K);
#pragma unroll
    for (int ni = 0; ni < 4; ++ni) {
      const int o = otile + ni * 16 + lc;
      const float bb = bias[o];
      const int n = o >> 6, d = o & 63;
#pragma unroll
      for (int mi = 0; mi < 2; ++mi)
#pragma unroll
        for (int r = 0; r < 4; ++r) {
          const int s = stile + mi * 16 + lr * 4 + r;
          dst[((size_t)(b * 4 + n) * 4096 + s) * 64 + d] =
              (__bf16)((acc[mi][ni][r] + bb) * scale);
        }
    }
  } else {
    const int otile = (bx & 3) * 64;
    const int stile = (bx >> 2) * 128 + w * 32;
    f32x4 acc[4][2];
#pragma unroll
    for (int i = 0; i < 4; ++i)
#pragma unroll
      for (int j = 0; j < 2; ++j) acc[i][j] = f32x4{0.f, 0.f, 0.f, 0.f};
    for (int it = 0; it < 8; ++it) {
      const int c0 = it * 32 + lr * 8;
      s16x8 af[4], bfr[2];
#pragma unroll
      for (int mi = 0; mi < 4; ++mi)
        af[mi] = *(const s16x8*)(W + (size_t)(otile + mi * 16 + lc) * 256 + c0);
#pragma unroll
      for (int ni = 0; ni < 2; ++ni)
        bfr[ni] = *(const s16x8*)(XT + (size_t)(stile + ni * 16 + lc) * 256 + c0);
#pragma unroll
      for (int mi = 0; mi < 4; ++mi)
#pragma unroll
        for (int ni = 0; ni < 2; ++ni)
          acc[mi][ni] = MFMA_BF16(af[mi], bfr[ni], acc[mi][ni]);
    }
    __bf16* dst = wsw + OFF_V;
#pragma unroll
    for (int mi = 0; mi < 4; ++mi)
#pragma unroll
      for (int r = 0; r < 4; ++r) {
        const int o = otile + mi * 16 + lr * 4 + r;
        const float bb = bias[o];
        const int n = o >> 6, d = o & 63;
#pragma unroll
        for (int ni = 0; ni < 2; ++ni) {
          const int s = stile + ni * 16 + lc;
          dst[((size_t)(b * 4 + n) * 64 + d) * 4096 + s] = (__bf16)(acc[mi][ni][r] + bb);
        }
      }
  }
}

// =====================================================================
// attn v2: swapped-QK flash attention, grid (64,8) block 512 (8 waves).
// Waves 0-3: even 64-wide j-tiles; 4-7: odd. Double-buffered K/V (one
// barrier/iter), XOR-swizzled unpadded LDS, exp2 softmax, defer-max.
// LDS layout: K[tg][buf][64*128B] @0 (32KB) | V same @32768 | P[8][2KB] @65536
// =====================================================================
__global__ __launch_bounds__(512) void attn_kernel(
    const __bf16* __restrict__ wsr, __bf16* __restrict__ wsw) {
  __shared__ __align__(16) unsigned char smem[81920];
  unsigned char* const Kb = smem;            // 32768: tg*16384 + buf*8192
  unsigned char* const Vb = smem + 32768;    // 32768: tg*16384 + buf*8192
  unsigned char* const Pb = smem + 65536;    // 16384
  float* const Mg = (float*)smem;            // alias K region after loop

  const int t = threadIdx.x;        // 0..511
  const int l = t & 63;
  const int w = t >> 6;             // 0..7
  const int g = w >> 2;             // j-parity group
  const int wq = w & 3;             // q-row subtile
  const int lr = l >> 4, lc = l & 15;
  const int bh = blockIdx.y;        // b*4 + n
  const int qbase = blockIdx.x * 64;

  const __bf16* Q = wsr + OFF_Q + (size_t)bh * (4096 * 64);
  const __bf16* K = wsr + OFF_K + (size_t)bh * (4096 * 64);
  const __bf16* V = wsr + OFF_V + (size_t)bh * (64 * 4096);

  // Q fragment (B-operand): n=q=lc, k=d=lr*8+j
  s16x8 aq[2];
#pragma unroll
  for (int kb = 0; kb < 2; ++kb)
    aq[kb] = *(const s16x8*)(Q + (size_t)(qbase + wq * 16 + lc) * 64 + kb * 32 + lr * 8);

  f32x4 o4[4];
#pragma unroll
  for (int i = 0; i < 4; ++i) o4[i] = f32x4{0.f, 0.f, 0.f, 0.f};
  float m = -1e30f, lsum = 0.f;     // state for q-row = lc (of this wave's subtile)

  unsigned char* const Pw = Pb + w * 2048;
  const int lcx = lc & 7;

  // staging ids: t covers row=t>>3 (0..63), ch=t&7; 4 tiles via 4 regs
  const int srow = t >> 3, sch = t & 7;
  const int soff = srow * 128 + ((sch ^ (srow & 7)) * 16);
  s16x8 pr0, pr1, pr2, pr3;

  // prologue: tiles jb=0 (tg0) and jb=64 (tg1) into buf0
  {
    pr0 = *(const s16x8*)(K + (size_t)(srow) * 64 + sch * 8);
    pr1 = *(const s16x8*)(K + (size_t)(64 + srow) * 64 + sch * 8);
    pr2 = *(const s16x8*)(V + (size_t)srow * 4096 + sch * 8);
    pr3 = *(const s16x8*)(V + (size_t)srow * 4096 + 64 + sch * 8);
    *(s16x8*)(Kb + soff) = pr0;
    *(s16x8*)(Kb + 16384 + soff) = pr1;
    *(s16x8*)(Vb + soff) = pr2;
    *(s16x8*)(Vb + 16384 + soff) = pr3;
  }
  __syncthreads();

  int cur = 0;
#pragma unroll 1
  for (int it = 0; it < 32; ++it) {
    const bool more = (it + 1 < 32);
    if (more) {
      const int jb0 = (it + 1) * 128;
      pr0 = *(const s16x8*)(K + (size_t)(jb0 + srow) * 64 + sch * 8);
      pr1 = *(const s16x8*)(K + (size_t)(jb0 + 64 + srow) * 64 + sch * 8);
      pr2 = *(const s16x8*)(V + (size_t)srow * 4096 + jb0 + sch * 8);
      pr3 = *(const s16x8*)(V + (size_t)srow * 4096 + jb0 + 64 + sch * 8);
    }

    unsigned char* const kt = Kb + g * 16384 + cur * 8192;
    unsigned char* const vt = Vb + g * 16384 + cur * 8192;

    // ---- QK^T (swapped): s4[jt] row=j=lr*4+r, col=q=lc ----
    f32x4 s4[4];
    __builtin_amdgcn_s_setprio(1);
#pragma unroll
    for (int jt = 0; jt < 4; ++jt) {
      f32x4 a = f32x4{0.f, 0.f, 0.f, 0.f};
#pragma unroll
      for (int kb = 0; kb < 2; ++kb) {
        s16x8 bk = *(const s16x8*)(kt + (jt * 16 + lc) * 128 + (((kb * 4 + lr) ^ lcx) * 16));
        a = MFMA_BF16(bk, aq[kb], a);
      }
      s4[jt] = a;
    }
    __builtin_amdgcn_s_setprio(0);

    // ---- online softmax, all for q=lc, j across regs + lanes lr ----
    float pmax = fmaxf(fmaxf(fmaxf(s4[0][0], s4[0][1]), fmaxf(s4[0][2], s4[0][3])),
                       fmaxf(fmaxf(s4[1][0], s4[1][1]), fmaxf(s4[1][2], s4[1][3])));
    pmax = fmaxf(pmax,
                 fmaxf(fmaxf(fmaxf(s4[2][0], s4[2][1]), fmaxf(s4[2][2], s4[2][3])),
                       fmaxf(fmaxf(s4[3][0], s4[3][1]), fmaxf(s4[3][2], s4[3][3]))));
    pmax = fmaxf(pmax, __shfl_xor(pmax, 16));
    pmax = fmaxf(pmax, __shfl_xor(pmax, 32));

    if (!__all(pmax - m <= 12.0f)) {   // defer-max: rescale only on real growth
      const float mn = fmaxf(m, pmax);
      const float f = EXP2(m - mn);
      m = mn;
      lsum *= f;
      float fb[4];
#pragma unroll
      for (int r = 0; r < 4; ++r) fb[r] = __shfl(f, lr * 4 + r);
#pragma unroll
      for (int nt = 0; nt < 4; ++nt)
#pragma unroll
        for (int r = 0; r < 4; ++r) o4[nt][r] *= fb[r];
    }

    float rs = 0.f;
#pragma unroll
    for (int jt = 0; jt < 4; ++jt) {
      union { __bf16 h[4]; unsigned long long u; } pk4;
      float p0 = EXP2(s4[jt][0] - m);
      float p1 = EXP2(s4[jt][1] - m);
      float p2 = EXP2(s4[jt][2] - m);
      float p3 = EXP2(s4[jt][3] - m);
      rs += (p0 + p1) + (p2 + p3);
      pk4.h[0] = (__bf16)p0; pk4.h[1] = (__bf16)p1;
      pk4.h[2] = (__bf16)p2; pk4.h[3] = (__bf16)p3;
      *(unsigned long long*)(Pw + lc * 128 + (((2 * jt + (lr >> 1)) ^ lcx) * 16) + (lr & 1) * 8) = pk4.u;
    }
    rs += __shfl_xor(rs, 16);
    rs += __shfl_xor(rs, 32);
    lsum += rs;

    // ---- PV: A=P (m=q rows), B=V (n=d cols) ----
    __builtin_amdgcn_s_setprio(1);
#pragma unroll
    for (int kb = 0; kb < 2; ++kb) {
      s16x8 pa = *(const s16x8*)(Pw + lc * 128 + (((kb * 4 + lr) ^ lcx) * 16));
#pragma unroll
      for (int nt = 0; nt < 4; ++nt) {
        s16x8 bv = *(const s16x8*)(vt + (nt * 16 + lc) * 128 + (((kb * 4 + lr) ^ lcx) * 16));
        o4[nt] = MFMA_BF16(pa, bv, o4[nt]);
      }
    }
    __builtin_amdgcn_s_setprio(0);

    if (more) {
      unsigned char* const kwr = Kb + (cur ^ 1) * 8192;
      unsigned char* const vwr = Vb + (cur ^ 1) * 8192;
      *(s16x8*)(kwr + soff) = pr0;
      *(s16x8*)(kwr + 16384 + soff) = pr1;
      *(s16x8*)(vwr + soff) = pr2;
      *(s16x8*)(vwr + 16384 + soff) = pr3;
    }
    __syncthreads();
    cur ^= 1;
  }

  // o4[nt][r] = out[q=lr*4+r][d=nt*16+lc]; per-lane state is for q=lc.
  float m4[4], l4[4];
#pragma unroll
  for (int r = 0; r < 4; ++r) {
    m4[r] = __shfl(m, lr * 4 + r);
    l4[r] = __shfl(lsum, lr * 4 + r);
  }

  // merge two j-groups via LDS (alias over K region; all KV reads done)
  if (g == 1) {
#pragma unroll
    for (int nt = 0; nt < 4; ++nt)
#pragma unroll
      for (int r = 0; r < 4; ++r)
        Mg[(wq * 16 + lr * 4 + r) * 66 + nt * 16 + lc] = o4[nt][r];
    if (lc == 0) {
#pragma unroll
      for (int r = 0; r < 4; ++r) {
        Mg[(wq * 16 + lr * 4 + r) * 66 + 64] = m4[r];
        Mg[(wq * 16 + lr * 4 + r) * 66 + 65] = l4[r];
      }
    }
  }
  __syncthreads();
  if (g == 0) {
    const int b = bh >> 2, n = bh & 3;
    __bf16* AO = wsw + OFF_AO + (size_t)b * (4096 * 256);
#pragma unroll
    for (int r = 0; r < 4; ++r) {
      const int row = wq * 16 + lr * 4 + r;
      const float m2 = Mg[row * 66 + 64];
      const float l2 = Mg[row * 66 + 65];
      const float M = fmaxf(m4[r], m2);
      const float f1 = EXP2(m4[r] - M);
      const float f2 = EXP2(m2 - M);
      const float linv = 1.0f / (l4[r] * f1 + l2 * f2);
      const int s = qbase + row;
#pragma unroll
      for (int nt = 0; nt < 4; ++nt) {
        const float val = (o4[nt][r] * f1 + Mg[row * 66 + nt * 16 + lc] * f2) * linv;
        AO[(size_t)s * 256 + n * 64 + nt * 16 + lc] = (__bf16)val;
      }
    }
  }
}

// =====================================================================
// outproj: out[b][o][s] = Wo . AO^T + bo   grid (128, 2) block 256
// =====================================================================
__global__ __launch_bounds__(256) void outproj_kernel(
    const __bf16* __restrict__ wsr, const float* __restrict__ bo,
    float* __restrict__ out) {
  const int b = blockIdx.y;
  const int bx = blockIdx.x;
  const int t = threadIdx.x;
  const int l = t & 63;
  const int w = t >> 6;
  const int lr = l >> 4, lc = l & 15;
  const int otile = (bx & 1) * 128 + w * 32;
  const int stile = (bx >> 1) * 64;
  const __bf16* Wo = wsr + OFF_WO;
  const __bf16* AO = wsr + OFF_AO + (size_t)b * 1048576;

  f32x4 acc[2][4];
#pragma unroll
  for (int i = 0; i < 2; ++i)
#pragma unroll
    for (int j = 0; j < 4; ++j) acc[i][j] = f32x4{0.f, 0.f, 0.f, 0.f};

  for (int it = 0; it < 8; ++it) {
    const int c0 = it * 32 + lr * 8;
    s16x8 af[2], bfr[4];
#pragma unroll
    for (int mi = 0; mi < 2; ++mi)
      af[mi] = *(const s16x8*)(Wo + (size_t)(otile + mi * 16 + lc) * 256 + c0);
#pragma unroll
    for (int ni = 0; ni < 4; ++ni)
      bfr[ni] = *(const s16x8*)(AO + (size_t)(stile + ni * 16 + lc) * 256 + c0);
#pragma unroll
    for (int mi = 0; mi < 2; ++mi)
#pragma unroll
      for (int ni = 0; ni < 4; ++ni)
        acc[mi][ni] = MFMA_BF16(af[mi], bfr[ni], acc[mi][ni]);
  }
#pragma unroll
  for (int mi = 0; mi < 2; ++mi)
#pragma unroll
    for (int r = 0; r < 4; ++r) {
      const int o = otile + mi * 16 + lr * 4 + r;
      const float bb = bo[o];
#pragma unroll
      for (int ni = 0; ni < 4; ++ni) {
        const int s = stile + ni * 16 + lc;
        out[((size_t)b * 256 + o) * 4096 + s] = acc[mi][ni][r] + bb;
      }
    }
}

// =====================================================================
extern "C" void kernel_launch(void* const* d_in, const int* in_sizes, int n_in,
                              void* d_out, int out_size, void* d_ws, size_t ws_size,
                              hipStream_t stream) {
  const float* xq  = (const float*)d_in[0];
  const float* xkv = (const float*)d_in[1];
  const float* wq  = (const float*)d_in[2];
  const float* bq  = (const float*)d_in[3];
  const float* wk  = (const float*)d_in[4];
  const float* bk  = (const float*)d_in[5];
  const float* wv  = (const float*)d_in[6];
  const float* bv  = (const float*)d_in[7];
  const float* wo  = (const float*)d_in[8];
  const float* bo  = (const float*)d_in[9];
  __bf16* ws = (__bf16*)d_ws;
  float* out = (float*)d_out;

  prep_kernel<<<dim3(512, 1, 3), 256, 0, stream>>>(xq, xkv, wq, wk, wv, wo, ws);
  proj_kernel<<<dim3(128, 1, 6), 256, 0, stream>>>(ws, ws, bq, bk, bv);
  attn_kernel<<<dim3(64, 8), 512, 0, stream>>>(ws, ws);
  outproj_kernel<<<dim3(128, 2), 256, 0, stream>>>(ws, bo, out);
}

// Round 8
// 155.678 us; speedup vs baseline: 1.5804x; 1.0817x over previous
//
#include <hip/hip_runtime.h>
#include <hip/hip_bf16.h>
#include <type_traits>
#include <cstdint>

typedef float  f32x4  __attribute__((ext_vector_type(4)));
typedef short  s16x8  __attribute__((ext_vector_type(8)));
typedef __bf16 bf16x8 __attribute__((ext_vector_type(8)));

#if __has_builtin(__builtin_amdgcn_exp2f)
#define EXP2(x) __builtin_amdgcn_exp2f(x)
#else
#define EXP2(x) exp2f(x)
#endif

// ---- MFMA wrapper: tolerant to builtin taking v8i16 or v8bf16 ----
template <typename V>
__device__ static inline auto mfma_try(V a, V b, f32x4 c, int)
    -> decltype(__builtin_amdgcn_mfma_f32_16x16x32_bf16(a, b, c, 0, 0, 0)) {
  return __builtin_amdgcn_mfma_f32_16x16x32_bf16(a, b, c, 0, 0, 0);
}
template <typename V>
__device__ static inline f32x4 mfma_try(V a, V b, f32x4 c, long) {
  return __builtin_amdgcn_mfma_f32_16x16x32_bf16(
      __builtin_bit_cast(bf16x8, a), __builtin_bit_cast(bf16x8, b), c, 0, 0, 0);
}
__device__ static inline f32x4 MFMA_BF16(s16x8 a, s16x8 b, f32x4 c) {
  return mfma_try(a, b, c, 0);
}

// ---- workspace layout (bf16 element offsets) ----
static constexpr size_t OFF_XTQ  = 0;         // [2][4096][256]
static constexpr size_t OFF_XTKV = 2097152;   // [2][4096][256]
static constexpr size_t OFF_WQ   = 4194304;   // [256][256]
static constexpr size_t OFF_WK   = 4259840;
static constexpr size_t OFF_WV   = 4325376;
static constexpr size_t OFF_WO   = 4390912;
static constexpr size_t OFF_Q    = 4456448;   // [2][4][4096][64]  (pre-scaled by 0.125*log2e)
static constexpr size_t OFF_K    = 6553600;   // [2][4][4096][64]
static constexpr size_t OFF_V    = 8650752;   // [2][4][64][4096]
static constexpr size_t OFF_AO   = 10747904;  // [2][4096][256]

// =====================================================================
// prep: transpose+cvt x_q/x_kv [C][S]f32 -> [S][C]bf16 ; cvt weights
// =====================================================================
__global__ __launch_bounds__(256) void prep_kernel(
    const float* __restrict__ xq, const float* __restrict__ xkv,
    const float* __restrict__ wq, const float* __restrict__ wk,
    const float* __restrict__ wv, const float* __restrict__ wo,
    __bf16* __restrict__ ws) {
  __shared__ __bf16 lds[64 * 66];
  const int t = threadIdx.x;
  const int z = blockIdx.z;
  if (z < 2) {
    const float* src = (z == 0) ? xq : xkv;
    __bf16* dst = ws + ((z == 0) ? OFF_XTQ : OFF_XTKV);
    const int id = blockIdx.x;
    const int b  = id >> 8;
    const int t2 = id & 255;
    const int ct = (t2 & 3) * 64;
    const int st = (t2 >> 2) * 64;
    const float* sb = src + (size_t)b * 1048576;
    __bf16* db = dst + (size_t)b * 1048576;
    const int l = t & 63;
    const int g = t >> 6;
#pragma unroll
    for (int r = 0; r < 16; ++r) {
      const int c = g * 16 + r;
      lds[c * 66 + l] = (__bf16)sb[(size_t)(ct + c) * 4096 + st + l];
    }
    __syncthreads();
#pragma unroll
    for (int r = 0; r < 16; ++r) {
      const int s = g * 16 + r;
      db[(size_t)(st + s) * 256 + ct + l] = lds[l * 66 + s];
    }
  } else {
    const int e0 = blockIdx.x * 512 + t;
#pragma unroll
    for (int p = 0; p < 2; ++p) {
      const int e = e0 + p * 256;
      const int m = e >> 16;
      const int idx = e & 65535;
      const float* w = (m == 0) ? wq : (m == 1) ? wk : (m == 2) ? wv : wo;
      ws[OFF_WQ + (size_t)m * 65536 + idx] = (__bf16)w[idx];
    }
  }
}

// =====================================================================
// proj: z = proj*2+b, proj 0=q,1=k (M=s,N=o), 2=v (M=o,N=s)
// grid (128,1,6) block 256; wave-tile 32x64.
// Block-shared W tile [64][256] staged once in LDS with chunk-XOR swizzle
// (phys_ch = ch ^ (row&7)) -> inner-loop b128 reads at the bank floor.
// =====================================================================
__global__ __launch_bounds__(256) void proj_kernel(
    const __bf16* __restrict__ wsr, __bf16* __restrict__ wsw,
    const float* __restrict__ bq, const float* __restrict__ bk,
    const float* __restrict__ bv) {
  __shared__ __align__(16) unsigned char Wl[64 * 512];  // 32KB
  const int z = blockIdx.z;
  const int proj = z >> 1;
  const int b = z & 1;
  const int t = threadIdx.x;
  const int l = t & 63;
  const int w = t >> 6;
  const int lr = l >> 4, lc = l & 15;
  const int bx = blockIdx.x;

  const __bf16* XT = wsr + ((proj == 0) ? OFF_XTQ : OFF_XTKV) + (size_t)b * 1048576;
  const __bf16* W  = wsr + ((proj == 0) ? OFF_WQ : (proj == 1) ? OFF_WK : OFF_WV);
  const float* bias = (proj == 0) ? bq : (proj == 1) ? bk : bv;

  const int otile = (bx & 3) * 64;
  // stage W rows [otile .. otile+63] (shared by all 4 waves)
#pragma unroll
  for (int p = 0; p < 8; ++p) {
    const int id = p * 256 + t;           // 0..2047
    const int row = id >> 5, ch = id & 31;
    *(s16x8*)(Wl + row * 512 + ((ch ^ (row & 7)) * 16)) =
        *(const s16x8*)(W + (size_t)(otile + row) * 256 + ch * 8);
  }
  __syncthreads();
  const int lcx = lc & 7;

  if (proj < 2) {
    const int stile = (bx >> 2) * 128 + w * 32;
    f32x4 acc[2][4];
#pragma unroll
    for (int i = 0; i < 2; ++i)
#pragma unroll
      for (int j = 0; j < 4; ++j) acc[i][j] = f32x4{0.f, 0.f, 0.f, 0.f};
    for (int it = 0; it < 8; ++it) {
      const int c0 = it * 32 + lr * 8;
      s16x8 af[2], bfr[4];
#pragma unroll
      for (int mi = 0; mi < 2; ++mi)
        af[mi] = *(const s16x8*)(XT + (size_t)(stile + mi * 16 + lc) * 256 + c0);
#pragma unroll
      for (int ni = 0; ni < 4; ++ni)
        bfr[ni] = *(const s16x8*)(Wl + (ni * 16 + lc) * 512 + (((it * 4 + lr) ^ lcx) * 16));
#pragma unroll
      for (int mi = 0; mi < 2; ++mi)
#pragma unroll
        for (int ni = 0; ni < 4; ++ni)
          acc[mi][ni] = MFMA_BF16(af[mi], bfr[ni], acc[mi][ni]);
    }
    // Q carries attn scale AND log2(e) so attn can use exp2 directly
    const float scale = (proj == 0) ? 0.125f * 1.44269504088896f : 1.0f;
    __bf16* dst = wsw + ((proj == 0) ? OFF_Q : OFF_K);
#pragma unroll
    for (int ni = 0; ni < 4; ++ni) {
      const int o = otile + ni * 16 + lc;
      const float bb = bias[o];
      const int n = o >> 6, d = o & 63;
#pragma unroll
      for (int mi = 0; mi < 2; ++mi)
#pragma unroll
        for (int r = 0; r < 4; ++r) {
          const int s = stile + mi * 16 + lr * 4 + r;
          dst[((size_t)(b * 4 + n) * 4096 + s) * 64 + d] =
              (__bf16)((acc[mi][ni][r] + bb) * scale);
        }
    }
  } else {
    const int stile = (bx >> 2) * 128 + w * 32;
    f32x4 acc[4][2];
#pragma unroll
    for (int i = 0; i < 4; ++i)
#pragma unroll
      for (int j = 0; j < 2; ++j) acc[i][j] = f32x4{0.f, 0.f, 0.f, 0.f};
    for (int it = 0; it < 8; ++it) {
      const int c0 = it * 32 + lr * 8;
      s16x8 af[4], bfr[2];
#pragma unroll
      for (int mi = 0; mi < 4; ++mi)
        af[mi] = *(const s16x8*)(Wl + (mi * 16 + lc) * 512 + (((it * 4 + lr) ^ lcx) * 16));
#pragma unroll
      for (int ni = 0; ni < 2; ++ni)
        bfr[ni] = *(const s16x8*)(XT + (size_t)(stile + ni * 16 + lc) * 256 + c0);
#pragma unroll
      for (int mi = 0; mi < 4; ++mi)
#pragma unroll
        for (int ni = 0; ni < 2; ++ni)
          acc[mi][ni] = MFMA_BF16(af[mi], bfr[ni], acc[mi][ni]);
    }
    __bf16* dst = wsw + OFF_V;
#pragma unroll
    for (int mi = 0; mi < 4; ++mi)
#pragma unroll
      for (int r = 0; r < 4; ++r) {
        const int o = otile + mi * 16 + lr * 4 + r;
        const float bb = bias[o];
        const int n = o >> 6, d = o & 63;
#pragma unroll
        for (int ni = 0; ni < 2; ++ni) {
          const int s = stile + ni * 16 + lc;
          dst[((size_t)(b * 4 + n) * 64 + d) * 4096 + s] = (__bf16)(acc[mi][ni][r] + bb);
        }
      }
  }
}

// =====================================================================
// attn v2: swapped-QK flash attention, grid (64,8) block 512 (8 waves).
// Waves 0-3: even 64-wide j-tiles; 4-7: odd. Double-buffered K/V (one
// barrier/iter), XOR-swizzled unpadded LDS, exp2 softmax, defer-max.
// LDS layout: K[tg][buf][64*128B] @0 (32KB) | V same @32768 | P[8][2KB] @65536
// =====================================================================
__global__ __launch_bounds__(512) void attn_kernel(
    const __bf16* __restrict__ wsr, __bf16* __restrict__ wsw) {
  __shared__ __align__(16) unsigned char smem[81920];
  unsigned char* const Kb = smem;            // 32768: tg*16384 + buf*8192
  unsigned char* const Vb = smem + 32768;    // 32768: tg*16384 + buf*8192
  unsigned char* const Pb = smem + 65536;    // 16384
  float* const Mg = (float*)smem;            // alias K region after loop

  const int t = threadIdx.x;        // 0..511
  const int l = t & 63;
  const int w = t >> 6;             // 0..7
  const int g = w >> 2;             // j-parity group
  const int wq = w & 3;             // q-row subtile
  const int lr = l >> 4, lc = l & 15;
  const int bh = blockIdx.y;        // b*4 + n
  const int qbase = blockIdx.x * 64;

  const __bf16* Q = wsr + OFF_Q + (size_t)bh * (4096 * 64);
  const __bf16* K = wsr + OFF_K + (size_t)bh * (4096 * 64);
  const __bf16* V = wsr + OFF_V + (size_t)bh * (64 * 4096);

  // Q fragment (B-operand): n=q=lc, k=d=lr*8+j
  s16x8 aq[2];
#pragma unroll
  for (int kb = 0; kb < 2; ++kb)
    aq[kb] = *(const s16x8*)(Q + (size_t)(qbase + wq * 16 + lc) * 64 + kb * 32 + lr * 8);

  f32x4 o4[4];
#pragma unroll
  for (int i = 0; i < 4; ++i) o4[i] = f32x4{0.f, 0.f, 0.f, 0.f};
  float m = -1e30f, lsum = 0.f;     // state for q-row = lc (of this wave's subtile)

  unsigned char* const Pw = Pb + w * 2048;
  const int lcx = lc & 7;

  // staging ids: t covers row=t>>3 (0..63), ch=t&7; 4 tiles via 4 regs
  const int srow = t >> 3, sch = t & 7;
  const int soff = srow * 128 + ((sch ^ (srow & 7)) * 16);
  s16x8 pr0, pr1, pr2, pr3;

  // prologue: tiles jb=0 (tg0) and jb=64 (tg1) into buf0
  {
    pr0 = *(const s16x8*)(K + (size_t)(srow) * 64 + sch * 8);
    pr1 = *(const s16x8*)(K + (size_t)(64 + srow) * 64 + sch * 8);
    pr2 = *(const s16x8*)(V + (size_t)srow * 4096 + sch * 8);
    pr3 = *(const s16x8*)(V + (size_t)srow * 4096 + 64 + sch * 8);
    *(s16x8*)(Kb + soff) = pr0;
    *(s16x8*)(Kb + 16384 + soff) = pr1;
    *(s16x8*)(Vb + soff) = pr2;
    *(s16x8*)(Vb + 16384 + soff) = pr3;
  }
  __syncthreads();

  int cur = 0;
#pragma unroll 1
  for (int it = 0; it < 32; ++it) {
    const bool more = (it + 1 < 32);
    if (more) {
      const int jb0 = (it + 1) * 128;
      pr0 = *(const s16x8*)(K + (size_t)(jb0 + srow) * 64 + sch * 8);
      pr1 = *(const s16x8*)(K + (size_t)(jb0 + 64 + srow) * 64 + sch * 8);
      pr2 = *(const s16x8*)(V + (size_t)srow * 4096 + jb0 + sch * 8);
      pr3 = *(const s16x8*)(V + (size_t)srow * 4096 + jb0 + 64 + sch * 8);
    }

    unsigned char* const kt = Kb + g * 16384 + cur * 8192;
    unsigned char* const vt = Vb + g * 16384 + cur * 8192;

    // ---- QK^T (swapped): s4[jt] row=j=lr*4+r, col=q=lc ----
    f32x4 s4[4];
    __builtin_amdgcn_s_setprio(1);
#pragma unroll
    for (int jt = 0; jt < 4; ++jt) {
      f32x4 a = f32x4{0.f, 0.f, 0.f, 0.f};
#pragma unroll
      for (int kb = 0; kb < 2; ++kb) {
        s16x8 bk = *(const s16x8*)(kt + (jt * 16 + lc) * 128 + (((kb * 4 + lr) ^ lcx) * 16));
        a = MFMA_BF16(bk, aq[kb], a);
      }
      s4[jt] = a;
    }
    __builtin_amdgcn_s_setprio(0);

    // ---- online softmax, all for q=lc, j across regs + lanes lr ----
    float pmax = fmaxf(fmaxf(fmaxf(s4[0][0], s4[0][1]), fmaxf(s4[0][2], s4[0][3])),
                       fmaxf(fmaxf(s4[1][0], s4[1][1]), fmaxf(s4[1][2], s4[1][3])));
    pmax = fmaxf(pmax,
                 fmaxf(fmaxf(fmaxf(s4[2][0], s4[2][1]), fmaxf(s4[2][2], s4[2][3])),
                       fmaxf(fmaxf(s4[3][0], s4[3][1]), fmaxf(s4[3][2], s4[3][3]))));
    pmax = fmaxf(pmax, __shfl_xor(pmax, 16));
    pmax = fmaxf(pmax, __shfl_xor(pmax, 32));

    if (!__all(pmax - m <= 12.0f)) {   // defer-max: rescale only on real growth
      const float mn = fmaxf(m, pmax);
      const float f = EXP2(m - mn);
      m = mn;
      lsum *= f;
      float fb[4];
#pragma unroll
      for (int r = 0; r < 4; ++r) fb[r] = __shfl(f, lr * 4 + r);
#pragma unroll
      for (int nt = 0; nt < 4; ++nt)
#pragma unroll
        for (int r = 0; r < 4; ++r) o4[nt][r] *= fb[r];
    }

    float rs = 0.f;
#pragma unroll
    for (int jt = 0; jt < 4; ++jt) {
      union { __bf16 h[4]; unsigned long long u; } pk4;
      float p0 = EXP2(s4[jt][0] - m);
      float p1 = EXP2(s4[jt][1] - m);
      float p2 = EXP2(s4[jt][2] - m);
      float p3 = EXP2(s4[jt][3] - m);
      rs += (p0 + p1) + (p2 + p3);
      pk4.h[0] = (__bf16)p0; pk4.h[1] = (__bf16)p1;
      pk4.h[2] = (__bf16)p2; pk4.h[3] = (__bf16)p3;
      *(unsigned long long*)(Pw + lc * 128 + (((2 * jt + (lr >> 1)) ^ lcx) * 16) + (lr & 1) * 8) = pk4.u;
    }
    rs += __shfl_xor(rs, 16);
    rs += __shfl_xor(rs, 32);
    lsum += rs;

    // ---- PV: A=P (m=q rows), B=V (n=d cols) ----
    __builtin_amdgcn_s_setprio(1);
#pragma unroll
    for (int kb = 0; kb < 2; ++kb) {
      s16x8 pa = *(const s16x8*)(Pw + lc * 128 + (((kb * 4 + lr) ^ lcx) * 16));
#pragma unroll
      for (int nt = 0; nt < 4; ++nt) {
        s16x8 bv = *(const s16x8*)(vt + (nt * 16 + lc) * 128 + (((kb * 4 + lr) ^ lcx) * 16));
        o4[nt] = MFMA_BF16(pa, bv, o4[nt]);
      }
    }
    __builtin_amdgcn_s_setprio(0);

    if (more) {
      unsigned char* const kwr = Kb + (cur ^ 1) * 8192;
      unsigned char* const vwr = Vb + (cur ^ 1) * 8192;
      *(s16x8*)(kwr + soff) = pr0;
      *(s16x8*)(kwr + 16384 + soff) = pr1;
      *(s16x8*)(vwr + soff) = pr2;
      *(s16x8*)(vwr + 16384 + soff) = pr3;
    }
    __syncthreads();
    cur ^= 1;
  }

  // o4[nt][r] = out[q=lr*4+r][d=nt*16+lc]; per-lane state is for q=lc.
  float m4[4], l4[4];
#pragma unroll
  for (int r = 0; r < 4; ++r) {
    m4[r] = __shfl(m, lr * 4 + r);
    l4[r] = __shfl(lsum, lr * 4 + r);
  }

  // merge two j-groups via LDS (alias over K region; all KV reads done)
  if (g == 1) {
#pragma unroll
    for (int nt = 0; nt < 4; ++nt)
#pragma unroll
      for (int r = 0; r < 4; ++r)
        Mg[(wq * 16 + lr * 4 + r) * 66 + nt * 16 + lc] = o4[nt][r];
    if (lc == 0) {
#pragma unroll
      for (int r = 0; r < 4; ++r) {
        Mg[(wq * 16 + lr * 4 + r) * 66 + 64] = m4[r];
        Mg[(wq * 16 + lr * 4 + r) * 66 + 65] = l4[r];
      }
    }
  }
  __syncthreads();
  if (g == 0) {
    const int b = bh >> 2, n = bh & 3;
    __bf16* AO = wsw + OFF_AO + (size_t)b * (4096 * 256);
#pragma unroll
    for (int r = 0; r < 4; ++r) {
      const int row = wq * 16 + lr * 4 + r;
      const float m2 = Mg[row * 66 + 64];
      const float l2 = Mg[row * 66 + 65];
      const float M = fmaxf(m4[r], m2);
      const float f1 = EXP2(m4[r] - M);
      const float f2 = EXP2(m2 - M);
      const float linv = 1.0f / (l4[r] * f1 + l2 * f2);
      const int s = qbase + row;
#pragma unroll
      for (int nt = 0; nt < 4; ++nt) {
        const float val = (o4[nt][r] * f1 + Mg[row * 66 + nt * 16 + lc] * f2) * linv;
        AO[(size_t)s * 256 + n * 64 + nt * 16 + lc] = (__bf16)val;
      }
    }
  }
}

// =====================================================================
// outproj: out[b][o][s] = Wo . AO^T + bo   grid (128, 2) block 256
// Block-shared AO tile [64s][256c] staged once in LDS (XOR swizzle).
// =====================================================================
__global__ __launch_bounds__(256) void outproj_kernel(
    const __bf16* __restrict__ wsr, const float* __restrict__ bo,
    float* __restrict__ out) {
  __shared__ __align__(16) unsigned char AOl[64 * 512];  // 32KB
  const int b = blockIdx.y;
  const int bx = blockIdx.x;
  const int t = threadIdx.x;
  const int l = t & 63;
  const int w = t >> 6;
  const int lr = l >> 4, lc = l & 15;
  const int otile = (bx & 1) * 128 + w * 32;
  const int stile = (bx >> 1) * 64;
  const __bf16* Wo = wsr + OFF_WO;
  const __bf16* AO = wsr + OFF_AO + (size_t)b * 1048576;

  // stage AO rows [stile .. stile+63] (shared by all 4 waves)
#pragma unroll
  for (int p = 0; p < 8; ++p) {
    const int id = p * 256 + t;
    const int row = id >> 5, ch = id & 31;
    *(s16x8*)(AOl + row * 512 + ((ch ^ (row & 7)) * 16)) =
        *(const s16x8*)(AO + (size_t)(stile + row) * 256 + ch * 8);
  }
  __syncthreads();
  const int lcx = lc & 7;

  f32x4 acc[2][4];
#pragma unroll
  for (int i = 0; i < 2; ++i)
#pragma unroll
    for (int j = 0; j < 4; ++j) acc[i][j] = f32x4{0.f, 0.f, 0.f, 0.f};

  for (int it = 0; it < 8; ++it) {
    const int c0 = it * 32 + lr * 8;
    s16x8 af[2], bfr[4];
#pragma unroll
    for (int mi = 0; mi < 2; ++mi)
      af[mi] = *(const s16x8*)(Wo + (size_t)(otile + mi * 16 + lc) * 256 + c0);
#pragma unroll
    for (int ni = 0; ni < 4; ++ni)
      bfr[ni] = *(const s16x8*)(AOl + (ni * 16 + lc) * 512 + (((it * 4 + lr) ^ lcx) * 16));
#pragma unroll
    for (int mi = 0; mi < 2; ++mi)
#pragma unroll
      for (int ni = 0; ni < 4; ++ni)
        acc[mi][ni] = MFMA_BF16(af[mi], bfr[ni], acc[mi][ni]);
  }
#pragma unroll
  for (int mi = 0; mi < 2; ++mi)
#pragma unroll
    for (int r = 0; r < 4; ++r) {
      const int o = otile + mi * 16 + lr * 4 + r;
      const float bb = bo[o];
#pragma unroll
      for (int ni = 0; ni < 4; ++ni) {
        const int s = stile + ni * 16 + lc;
        out[((size_t)b * 256 + o) * 4096 + s] = acc[mi][ni][r] + bb;
      }
    }
}

// =====================================================================
extern "C" void kernel_launch(void* const* d_in, const int* in_sizes, int n_in,
                              void* d_out, int out_size, void* d_ws, size_t ws_size,
                              hipStream_t stream) {
  const float* xq  = (const float*)d_in[0];
  const float* xkv = (const float*)d_in[1];
  const float* wq  = (const float*)d_in[2];
  const float* bq  = (const float*)d_in[3];
  const float* wk  = (const float*)d_in[4];
  const float* bk  = (const float*)d_in[5];
  const float* wv  = (const float*)d_in[6];
  const float* bv  = (const float*)d_in[7];
  const float* wo  = (const float*)d_in[8];
  const float* bo  = (const float*)d_in[9];
  __bf16* ws = (__bf16*)d_ws;
  float* out = (float*)d_out;

  prep_kernel<<<dim3(512, 1, 3), 256, 0, stream>>>(xq, xkv, wq, wk, wv, wo, ws);
  proj_kernel<<<dim3(128, 1, 6), 256, 0, stream>>>(ws, ws, bq, bk, bv);
  attn_kernel<<<dim3(64, 8), 512, 0, stream>>>(ws, ws);
  outproj_kernel<<<dim3(128, 2), 256, 0, stream>>>(ws, bo, out);
}

// Round 9
// 154.547 us; speedup vs baseline: 1.5920x; 1.0073x over previous
//
#include <hip/hip_runtime.h>
#include <hip/hip_bf16.h>
#include <type_traits>
#include <cstdint>

typedef float  f32x4  __attribute__((ext_vector_type(4)));
typedef short  s16x8  __attribute__((ext_vector_type(8)));
typedef __bf16 bf16x8 __attribute__((ext_vector_type(8)));

#if __has_builtin(__builtin_amdgcn_exp2f)
#define EXP2(x) __builtin_amdgcn_exp2f(x)
#else
#define EXP2(x) exp2f(x)
#endif

// ---- MFMA wrapper: tolerant to builtin taking v8i16 or v8bf16 ----
template <typename V>
__device__ static inline auto mfma_try(V a, V b, f32x4 c, int)
    -> decltype(__builtin_amdgcn_mfma_f32_16x16x32_bf16(a, b, c, 0, 0, 0)) {
  return __builtin_amdgcn_mfma_f32_16x16x32_bf16(a, b, c, 0, 0, 0);
}
template <typename V>
__device__ static inline f32x4 mfma_try(V a, V b, f32x4 c, long) {
  return __builtin_amdgcn_mfma_f32_16x16x32_bf16(
      __builtin_bit_cast(bf16x8, a), __builtin_bit_cast(bf16x8, b), c, 0, 0, 0);
}
__device__ static inline f32x4 MFMA_BF16(s16x8 a, s16x8 b, f32x4 c) {
  return mfma_try(a, b, c, 0);
}

// ---- workspace layout (bf16 element offsets) ----
static constexpr size_t OFF_XTQ  = 0;         // [2][4096][256]
static constexpr size_t OFF_XTKV = 2097152;   // [2][4096][256]
static constexpr size_t OFF_WQ   = 4194304;   // [256][256]
static constexpr size_t OFF_WK   = 4259840;
static constexpr size_t OFF_WV   = 4325376;
static constexpr size_t OFF_WO   = 4390912;
static constexpr size_t OFF_Q    = 4456448;   // [2][4][4096][64]  (pre-scaled by 0.125*log2e)
static constexpr size_t OFF_K    = 6553600;   // [2][4][4096][64]
static constexpr size_t OFF_V    = 8650752;   // [2][4][64][4096]
static constexpr size_t OFF_AO   = 10747904;  // [2][4096][256]

// =====================================================================
// prep: transpose+cvt x_q/x_kv [C][S]f32 -> [S][C]bf16 ; cvt weights
// transpose path: float4 loads -> f32 LDS (stride 67, 2-way banks) ->
// bf16x8 packed b128 stores. 6 VMEM instr/thread (was 32).
// =====================================================================
__global__ __launch_bounds__(256) void prep_kernel(
    const float* __restrict__ xq, const float* __restrict__ xkv,
    const float* __restrict__ wq, const float* __restrict__ wk,
    const float* __restrict__ wv, const float* __restrict__ wo,
    __bf16* __restrict__ ws) {
  __shared__ float xl[64 * 67];   // 17.2 KB
  const int t = threadIdx.x;
  const int z = blockIdx.z;
  if (z < 2) {
    const float* src = (z == 0) ? xq : xkv;
    __bf16* dst = ws + ((z == 0) ? OFF_XTQ : OFF_XTKV);
    const int id = blockIdx.x;
    const int b  = id >> 8;
    const int t2 = id & 255;
    const int ct = (t2 & 3) * 64;
    const int st = (t2 >> 2) * 64;
    const float* sb = src + (size_t)b * 1048576;
    __bf16* db = dst + (size_t)b * 1048576;
    const int cl = t >> 4;        // 0..15
    const int sq = t & 15;        // s-quad
#pragma unroll
    for (int p = 0; p < 4; ++p) {
      const int c = cl + p * 16;
      const f32x4 v = *(const f32x4*)(sb + (size_t)(ct + c) * 4096 + st + sq * 4);
      xl[(sq * 4 + 0) * 67 + c] = v[0];
      xl[(sq * 4 + 1) * 67 + c] = v[1];
      xl[(sq * 4 + 2) * 67 + c] = v[2];
      xl[(sq * 4 + 3) * 67 + c] = v[3];
    }
    __syncthreads();
#pragma unroll
    for (int q = 0; q < 2; ++q) {
      const int idq = q * 256 + t;
      const int s = idq >> 3, ch = idq & 7;
      union { __bf16 h[8]; s16x8 v; } o;
#pragma unroll
      for (int k = 0; k < 8; ++k) o.h[k] = (__bf16)xl[s * 67 + ch * 8 + k];
      *(s16x8*)(db + (size_t)(st + s) * 256 + ct + ch * 8) = o.v;
    }
  } else {
    const int e0 = blockIdx.x * 512 + t;
#pragma unroll
    for (int p = 0; p < 2; ++p) {
      const int e = e0 + p * 256;
      const int m = e >> 16;
      const int idx = e & 65535;
      const float* w = (m == 0) ? wq : (m == 1) ? wk : (m == 2) ? wv : wo;
      ws[OFF_WQ + (size_t)m * 65536 + idx] = (__bf16)w[idx];
    }
  }
}

// =====================================================================
// proj: z = proj*2+b, proj 0=q,1=k (M=s,N=o), 2=v (M=o,N=s)
// grid (128,1,6) block 256; wave-tile 32x64.
// Block-shared W tile [64][256] staged once in LDS (chunk-XOR swizzle);
// K-loop fully unrolled so global af loads software-pipeline.
// =====================================================================
__global__ __launch_bounds__(256) void proj_kernel(
    const __bf16* __restrict__ wsr, __bf16* __restrict__ wsw,
    const float* __restrict__ bq, const float* __restrict__ bk,
    const float* __restrict__ bv) {
  __shared__ __align__(16) unsigned char Wl[64 * 512];  // 32KB
  const int z = blockIdx.z;
  const int proj = z >> 1;
  const int b = z & 1;
  const int t = threadIdx.x;
  const int l = t & 63;
  const int w = t >> 6;
  const int lr = l >> 4, lc = l & 15;
  const int bx = blockIdx.x;

  const __bf16* XT = wsr + ((proj == 0) ? OFF_XTQ : OFF_XTKV) + (size_t)b * 1048576;
  const __bf16* W  = wsr + ((proj == 0) ? OFF_WQ : (proj == 1) ? OFF_WK : OFF_WV);
  const float* bias = (proj == 0) ? bq : (proj == 1) ? bk : bv;

  const int otile = (bx & 3) * 64;
  // stage W rows [otile .. otile+63] (shared by all 4 waves)
#pragma unroll
  for (int p = 0; p < 8; ++p) {
    const int id = p * 256 + t;           // 0..2047
    const int row = id >> 5, ch = id & 31;
    *(s16x8*)(Wl + row * 512 + ((ch ^ (row & 7)) * 16)) =
        *(const s16x8*)(W + (size_t)(otile + row) * 256 + ch * 8);
  }
  __syncthreads();
  const int lcx = lc & 7;

  if (proj < 2) {
    const int stile = (bx >> 2) * 128 + w * 32;
    f32x4 acc[2][4];
#pragma unroll
    for (int i = 0; i < 2; ++i)
#pragma unroll
      for (int j = 0; j < 4; ++j) acc[i][j] = f32x4{0.f, 0.f, 0.f, 0.f};
#pragma unroll
    for (int it = 0; it < 8; ++it) {
      const int c0 = it * 32 + lr * 8;
      s16x8 af[2], bfr[4];
#pragma unroll
      for (int mi = 0; mi < 2; ++mi)
        af[mi] = *(const s16x8*)(XT + (size_t)(stile + mi * 16 + lc) * 256 + c0);
#pragma unroll
      for (int ni = 0; ni < 4; ++ni)
        bfr[ni] = *(const s16x8*)(Wl + (ni * 16 + lc) * 512 + (((it * 4 + lr) ^ lcx) * 16));
#pragma unroll
      for (int mi = 0; mi < 2; ++mi)
#pragma unroll
        for (int ni = 0; ni < 4; ++ni)
          acc[mi][ni] = MFMA_BF16(af[mi], bfr[ni], acc[mi][ni]);
    }
    // Q carries attn scale AND log2(e) so attn can use exp2 directly
    const float scale = (proj == 0) ? 0.125f * 1.44269504088896f : 1.0f;
    __bf16* dst = wsw + ((proj == 0) ? OFF_Q : OFF_K);
#pragma unroll
    for (int ni = 0; ni < 4; ++ni) {
      const int o = otile + ni * 16 + lc;
      const float bb = bias[o];
      const int n = o >> 6, d = o & 63;
#pragma unroll
      for (int mi = 0; mi < 2; ++mi)
#pragma unroll
        for (int r = 0; r < 4; ++r) {
          const int s = stile + mi * 16 + lr * 4 + r;
          dst[((size_t)(b * 4 + n) * 4096 + s) * 64 + d] =
              (__bf16)((acc[mi][ni][r] + bb) * scale);
        }
    }
  } else {
    const int stile = (bx >> 2) * 128 + w * 32;
    f32x4 acc[4][2];
#pragma unroll
    for (int i = 0; i < 4; ++i)
#pragma unroll
      for (int j = 0; j < 2; ++j) acc[i][j] = f32x4{0.f, 0.f, 0.f, 0.f};
#pragma unroll
    for (int it = 0; it < 8; ++it) {
      const int c0 = it * 32 + lr * 8;
      s16x8 af[4], bfr[2];
#pragma unroll
      for (int mi = 0; mi < 4; ++mi)
        af[mi] = *(const s16x8*)(Wl + (mi * 16 + lc) * 512 + (((it * 4 + lr) ^ lcx) * 16));
#pragma unroll
      for (int ni = 0; ni < 2; ++ni)
        bfr[ni] = *(const s16x8*)(XT + (size_t)(stile + ni * 16 + lc) * 256 + c0);
#pragma unroll
      for (int mi = 0; mi < 4; ++mi)
#pragma unroll
        for (int ni = 0; ni < 2; ++ni)
          acc[mi][ni] = MFMA_BF16(af[mi], bfr[ni], acc[mi][ni]);
    }
    __bf16* dst = wsw + OFF_V;
#pragma unroll
    for (int mi = 0; mi < 4; ++mi)
#pragma unroll
      for (int r = 0; r < 4; ++r) {
        const int o = otile + mi * 16 + lr * 4 + r;
        const float bb = bias[o];
        const int n = o >> 6, d = o & 63;
#pragma unroll
        for (int ni = 0; ni < 2; ++ni) {
          const int s = stile + ni * 16 + lc;
          dst[((size_t)(b * 4 + n) * 64 + d) * 4096 + s] = (__bf16)(acc[mi][ni][r] + bb);
        }
      }
  }
}

// =====================================================================
// attn v3: swapped-QK flash attention, grid (512) block 512 (8 waves).
// head = bx&7  ->  all 64 q-blocks of a head share one XCD L2 (T1).
// Waves 0-3: even 64-wide j-tiles; 4-7: odd. Double-buffered K/V (one
// barrier/iter), XOR-swizzled unpadded LDS, exp2 softmax, defer-max.
// LDS layout: K[tg][buf][64*128B] @0 (32KB) | V same @32768 | P[8][2KB] @65536
// =====================================================================
__global__ __launch_bounds__(512) void attn_kernel(
    const __bf16* __restrict__ wsr, __bf16* __restrict__ wsw) {
  __shared__ __align__(16) unsigned char smem[81920];
  unsigned char* const Kb = smem;            // 32768: tg*16384 + buf*8192
  unsigned char* const Vb = smem + 32768;    // 32768: tg*16384 + buf*8192
  unsigned char* const Pb = smem + 65536;    // 16384
  float* const Mg = (float*)smem;            // alias K region after loop

  const int t = threadIdx.x;        // 0..511
  const int l = t & 63;
  const int w = t >> 6;             // 0..7
  const int g = w >> 2;             // j-parity group
  const int wq = w & 3;             // q-row subtile
  const int lr = l >> 4, lc = l & 15;
  const int bh = blockIdx.x & 7;    // b*4 + n  (low bits -> XCD clustering)
  const int qbase = (blockIdx.x >> 3) * 64;

  const __bf16* Q = wsr + OFF_Q + (size_t)bh * (4096 * 64);
  const __bf16* K = wsr + OFF_K + (size_t)bh * (4096 * 64);
  const __bf16* V = wsr + OFF_V + (size_t)bh * (64 * 4096);

  // Q fragment (B-operand): n=q=lc, k=d=lr*8+j
  s16x8 aq[2];
#pragma unroll
  for (int kb = 0; kb < 2; ++kb)
    aq[kb] = *(const s16x8*)(Q + (size_t)(qbase + wq * 16 + lc) * 64 + kb * 32 + lr * 8);

  f32x4 o4[4];
#pragma unroll
  for (int i = 0; i < 4; ++i) o4[i] = f32x4{0.f, 0.f, 0.f, 0.f};
  float m = -1e30f, lsum = 0.f;     // state for q-row = lc (of this wave's subtile)

  unsigned char* const Pw = Pb + w * 2048;
  const int lcx = lc & 7;

  // staging ids: t covers row=t>>3 (0..63), ch=t&7; 4 tiles via 4 regs
  const int srow = t >> 3, sch = t & 7;
  const int soff = srow * 128 + ((sch ^ (srow & 7)) * 16);
  s16x8 pr0, pr1, pr2, pr3;

  // prologue: tiles jb=0 (tg0) and jb=64 (tg1) into buf0
  {
    pr0 = *(const s16x8*)(K + (size_t)(srow) * 64 + sch * 8);
    pr1 = *(const s16x8*)(K + (size_t)(64 + srow) * 64 + sch * 8);
    pr2 = *(const s16x8*)(V + (size_t)srow * 4096 + sch * 8);
    pr3 = *(const s16x8*)(V + (size_t)srow * 4096 + 64 + sch * 8);
    *(s16x8*)(Kb + soff) = pr0;
    *(s16x8*)(Kb + 16384 + soff) = pr1;
    *(s16x8*)(Vb + soff) = pr2;
    *(s16x8*)(Vb + 16384 + soff) = pr3;
  }
  __syncthreads();

  int cur = 0;
#pragma unroll 1
  for (int it = 0; it < 32; ++it) {
    const bool more = (it + 1 < 32);
    if (more) {
      const int jb0 = (it + 1) * 128;
      pr0 = *(const s16x8*)(K + (size_t)(jb0 + srow) * 64 + sch * 8);
      pr1 = *(const s16x8*)(K + (size_t)(jb0 + 64 + srow) * 64 + sch * 8);
      pr2 = *(const s16x8*)(V + (size_t)srow * 4096 + jb0 + sch * 8);
      pr3 = *(const s16x8*)(V + (size_t)srow * 4096 + jb0 + 64 + sch * 8);
    }

    unsigned char* const kt = Kb + g * 16384 + cur * 8192;
    unsigned char* const vt = Vb + g * 16384 + cur * 8192;

    // ---- QK^T (swapped): s4[jt] row=j=lr*4+r, col=q=lc ----
    f32x4 s4[4];
    __builtin_amdgcn_s_setprio(1);
#pragma unroll
    for (int jt = 0; jt < 4; ++jt) {
      f32x4 a = f32x4{0.f, 0.f, 0.f, 0.f};
#pragma unroll
      for (int kb = 0; kb < 2; ++kb) {
        s16x8 bk = *(const s16x8*)(kt + (jt * 16 + lc) * 128 + (((kb * 4 + lr) ^ lcx) * 16));
        a = MFMA_BF16(bk, aq[kb], a);
      }
      s4[jt] = a;
    }
    __builtin_amdgcn_s_setprio(0);

    // ---- online softmax, all for q=lc, j across regs + lanes lr ----
    float pmax = fmaxf(fmaxf(fmaxf(s4[0][0], s4[0][1]), fmaxf(s4[0][2], s4[0][3])),
                       fmaxf(fmaxf(s4[1][0], s4[1][1]), fmaxf(s4[1][2], s4[1][3])));
    pmax = fmaxf(pmax,
                 fmaxf(fmaxf(fmaxf(s4[2][0], s4[2][1]), fmaxf(s4[2][2], s4[2][3])),
                       fmaxf(fmaxf(s4[3][0], s4[3][1]), fmaxf(s4[3][2], s4[3][3]))));
    pmax = fmaxf(pmax, __shfl_xor(pmax, 16));
    pmax = fmaxf(pmax, __shfl_xor(pmax, 32));

    if (!__all(pmax - m <= 12.0f)) {   // defer-max: rescale only on real growth
      const float mn = fmaxf(m, pmax);
      const float f = EXP2(m - mn);
      m = mn;
      lsum *= f;
      float fb[4];
#pragma unroll
      for (int r = 0; r < 4; ++r) fb[r] = __shfl(f, lr * 4 + r);
#pragma unroll
      for (int nt = 0; nt < 4; ++nt)
#pragma unroll
        for (int r = 0; r < 4; ++r) o4[nt][r] *= fb[r];
    }

    float rs = 0.f;
#pragma unroll
    for (int jt = 0; jt < 4; ++jt) {
      union { __bf16 h[4]; unsigned long long u; } pk4;
      float p0 = EXP2(s4[jt][0] - m);
      float p1 = EXP2(s4[jt][1] - m);
      float p2 = EXP2(s4[jt][2] - m);
      float p3 = EXP2(s4[jt][3] - m);
      rs += (p0 + p1) + (p2 + p3);
      pk4.h[0] = (__bf16)p0; pk4.h[1] = (__bf16)p1;
      pk4.h[2] = (__bf16)p2; pk4.h[3] = (__bf16)p3;
      *(unsigned long long*)(Pw + lc * 128 + (((2 * jt + (lr >> 1)) ^ lcx) * 16) + (lr & 1) * 8) = pk4.u;
    }
    rs += __shfl_xor(rs, 16);
    rs += __shfl_xor(rs, 32);
    lsum += rs;

    // ---- PV: A=P (m=q rows), B=V (n=d cols) ----
    __builtin_amdgcn_s_setprio(1);
#pragma unroll
    for (int kb = 0; kb < 2; ++kb) {
      s16x8 pa = *(const s16x8*)(Pw + lc * 128 + (((kb * 4 + lr) ^ lcx) * 16));
#pragma unroll
      for (int nt = 0; nt < 4; ++nt) {
        s16x8 bv = *(const s16x8*)(vt + (nt * 16 + lc) * 128 + (((kb * 4 + lr) ^ lcx) * 16));
        o4[nt] = MFMA_BF16(pa, bv, o4[nt]);
      }
    }
    __builtin_amdgcn_s_setprio(0);

    if (more) {
      unsigned char* const kwr = Kb + (cur ^ 1) * 8192;
      unsigned char* const vwr = Vb + (cur ^ 1) * 8192;
      *(s16x8*)(kwr + soff) = pr0;
      *(s16x8*)(kwr + 16384 + soff) = pr1;
      *(s16x8*)(vwr + soff) = pr2;
      *(s16x8*)(vwr + 16384 + soff) = pr3;
    }
    __syncthreads();
    cur ^= 1;
  }

  // o4[nt][r] = out[q=lr*4+r][d=nt*16+lc]; per-lane state is for q=lc.
  float m4[4], l4[4];
#pragma unroll
  for (int r = 0; r < 4; ++r) {
    m4[r] = __shfl(m, lr * 4 + r);
    l4[r] = __shfl(lsum, lr * 4 + r);
  }

  // merge two j-groups via LDS (alias over K region; all KV reads done)
  if (g == 1) {
#pragma unroll
    for (int nt = 0; nt < 4; ++nt)
#pragma unroll
      for (int r = 0; r < 4; ++r)
        Mg[(wq * 16 + lr * 4 + r) * 66 + nt * 16 + lc] = o4[nt][r];
    if (lc == 0) {
#pragma unroll
      for (int r = 0; r < 4; ++r) {
        Mg[(wq * 16 + lr * 4 + r) * 66 + 64] = m4[r];
        Mg[(wq * 16 + lr * 4 + r) * 66 + 65] = l4[r];
      }
    }
  }
  __syncthreads();
  if (g == 0) {
    const int b = bh >> 2, n = bh & 3;
    __bf16* AO = wsw + OFF_AO + (size_t)b * (4096 * 256);
#pragma unroll
    for (int r = 0; r < 4; ++r) {
      const int row = wq * 16 + lr * 4 + r;
      const float m2 = Mg[row * 66 + 64];
      const float l2 = Mg[row * 66 + 65];
      const float M = fmaxf(m4[r], m2);
      const float f1 = EXP2(m4[r] - M);
      const float f2 = EXP2(m2 - M);
      const float linv = 1.0f / (l4[r] * f1 + l2 * f2);
      const int s = qbase + row;
#pragma unroll
      for (int nt = 0; nt < 4; ++nt) {
        const float val = (o4[nt][r] * f1 + Mg[row * 66 + nt * 16 + lc] * f2) * linv;
        AO[(size_t)s * 256 + n * 64 + nt * 16 + lc] = (__bf16)val;
      }
    }
  }
}

// =====================================================================
// outproj: out[b][o][s] = Wo . AO^T + bo   grid (128, 2) block 256
// Block-shared AO tile [64s][256c] staged once in LDS (XOR swizzle);
// K-loop fully unrolled.
// =====================================================================
__global__ __launch_bounds__(256) void outproj_kernel(
    const __bf16* __restrict__ wsr, const float* __restrict__ bo,
    float* __restrict__ out) {
  __shared__ __align__(16) unsigned char AOl[64 * 512];  // 32KB
  const int b = blockIdx.y;
  const int bx = blockIdx.x;
  const int t = threadIdx.x;
  const int l = t & 63;
  const int w = t >> 6;
  const int lr = l >> 4, lc = l & 15;
  const int otile = (bx & 1) * 128 + w * 32;
  const int stile = (bx >> 1) * 64;
  const __bf16* Wo = wsr + OFF_WO;
  const __bf16* AO = wsr + OFF_AO + (size_t)b * 1048576;

  // stage AO rows [stile .. stile+63] (shared by all 4 waves)
#pragma unroll
  for (int p = 0; p < 8; ++p) {
    const int id = p * 256 + t;
    const int row = id >> 5, ch = id & 31;
    *(s16x8*)(AOl + row * 512 + ((ch ^ (row & 7)) * 16)) =
        *(const s16x8*)(AO + (size_t)(stile + row) * 256 + ch * 8);
  }
  __syncthreads();
  const int lcx = lc & 7;

  f32x4 acc[2][4];
#pragma unroll
  for (int i = 0; i < 2; ++i)
#pragma unroll
    for (int j = 0; j < 4; ++j) acc[i][j] = f32x4{0.f, 0.f, 0.f, 0.f};

#pragma unroll
  for (int it = 0; it < 8; ++it) {
    const int c0 = it * 32 + lr * 8;
    s16x8 af[2], bfr[4];
#pragma unroll
    for (int mi = 0; mi < 2; ++mi)
      af[mi] = *(const s16x8*)(Wo + (size_t)(otile + mi * 16 + lc) * 256 + c0);
#pragma unroll
    for (int ni = 0; ni < 4; ++ni)
      bfr[ni] = *(const s16x8*)(AOl + (ni * 16 + lc) * 512 + (((it * 4 + lr) ^ lcx) * 16));
#pragma unroll
    for (int mi = 0; mi < 2; ++mi)
#pragma unroll
      for (int ni = 0; ni < 4; ++ni)
        acc[mi][ni] = MFMA_BF16(af[mi], bfr[ni], acc[mi][ni]);
  }
#pragma unroll
  for (int mi = 0; mi < 2; ++mi)
#pragma unroll
    for (int r = 0; r < 4; ++r) {
      const int o = otile + mi * 16 + lr * 4 + r;
      const float bb = bo[o];
#pragma unroll
      for (int ni = 0; ni < 4; ++ni) {
        const int s = stile + ni * 16 + lc;
        out[((size_t)b * 256 + o) * 4096 + s] = acc[mi][ni][r] + bb;
      }
    }
}

// =====================================================================
extern "C" void kernel_launch(void* const* d_in, const int* in_sizes, int n_in,
                              void* d_out, int out_size, void* d_ws, size_t ws_size,
                              hipStream_t stream) {
  const float* xq  = (const float*)d_in[0];
  const float* xkv = (const float*)d_in[1];
  const float* wq  = (const float*)d_in[2];
  const float* bq  = (const float*)d_in[3];
  const float* wk  = (const float*)d_in[4];
  const float* bk  = (const float*)d_in[5];
  const float* wv  = (const float*)d_in[6];
  const float* bv  = (const float*)d_in[7];
  const float* wo  = (const float*)d_in[8];
  const float* bo  = (const float*)d_in[9];
  __bf16* ws = (__bf16*)d_ws;
  float* out = (float*)d_out;

  prep_kernel<<<dim3(512, 1, 3), 256, 0, stream>>>(xq, xkv, wq, wk, wv, wo, ws);
  proj_kernel<<<dim3(128, 1, 6), 256, 0, stream>>>(ws, ws, bq, bk, bv);
  attn_kernel<<<dim3(512), 512, 0, stream>>>(ws, ws);
  outproj_kernel<<<dim3(128, 2), 256, 0, stream>>>(ws, bo, out);
}